// Round 2
// baseline (736.665 us; speedup 1.0000x reference)
//
#include <hip/hip_runtime.h>
#include <hip/hip_bf16.h>
#include <math.h>

#define B_  2
#define T_  2048
#define D_  1024
#define F_  4096
#define E_  8
#define NTOK 4096       // B_*T_
#define TOPK 2
#define NROW 8192       // NTOK*TOPK total selected rows

typedef unsigned short bf16_t;
typedef float f32x4 __attribute__((ext_vector_type(4)));
typedef int   i32x4 __attribute__((ext_vector_type(4)));

// ---- ws layout (bytes) ----
#define OFF_CNT   0                          // int[8]
#define OFF_BASE  32                         // int[8]
#define OFF_TIDX  64                         // int[NTOK*2]
#define OFF_TW    32832                      // float[NTOK*2]
#define OFF_LIST  65600                      // int[8*4096]
#define OFF_WGT   196672                     // float[8*4096]
// old (round-2) path
#define OFF_H_OLD 327744                     // bf16[8192*4096] = 64 MB
#define WS_OLD    (OFF_H_OLD + (size_t)NROW * F_ * 2)
// MFMA path
#define OFF_SLOT  327744                     // int[NTOK*2]  (e<<16 | pos)
#define OFF_XB    (1u << 20)                 // bf16[NTOK*D]      8 MB
#define OFF_W1T   (OFF_XB  + (size_t)NTOK * D_ * 2)         // bf16[E*F*D] 64 MB
#define OFF_W2T   (OFF_W1T + (size_t)E_ * F_ * D_ * 2)      // bf16[E*D*F] 64 MB
#define OFF_HN    (OFF_W2T + (size_t)E_ * D_ * F_ * 2)      // bf16[NROW*F] 64 MB
#define OFF_Y     (OFF_HN  + (size_t)NROW * F_ * 2)         // f32[NROW*D] per slab
#define WS_MFMA   (OFF_Y + (size_t)NROW * D_ * 4)           // 1 slab
#define WS_MFMA2  (OFF_Y + 2 * (size_t)NROW * D_ * 4)       // 2 slabs

__device__ __forceinline__ float gelu_exact(float v) {
    return 0.5f * v * (1.0f + erff(v * 0.70710678118654752440f));
}

__device__ __forceinline__ unsigned short f2bf_rne(float f) {
    union { float f; unsigned int u; } v; v.f = f;
    unsigned int r = (v.u + 0x7fffu + ((v.u >> 16) & 1u)) >> 16;
    return (unsigned short)r;
}

__device__ __forceinline__ float bf2f(unsigned int u) {
    union { unsigned int i; float f; } v; v.i = u << 16; return v.f;
}

// async 16B/lane global->LDS; lds base wave-uniform (+lane*16 implicit)
__device__ __forceinline__ void gld16(const void* g, void* l) {
    __builtin_amdgcn_global_load_lds(
        (const __attribute__((address_space(1))) unsigned int*)g,
        (__attribute__((address_space(3))) unsigned int*)l, 16, 0, 0);
}

__device__ __forceinline__ void mfma16(const i32x4& a, const i32x4& b, f32x4& c) {
    asm("v_mfma_f32_16x16x32_bf16 %0, %1, %2, %0" : "+v"(c) : "v"(a), "v"(b));
}

// ---------------------------------------------------------------------------
// Router
// ---------------------------------------------------------------------------
__global__ __launch_bounds__(64) void router_kernel(
    const float* __restrict__ x, const float* __restrict__ Wr,
    int* __restrict__ top_idx, float* __restrict__ top_w,
    int* __restrict__ cnt, int* __restrict__ list, float* __restrict__ wgt,
    int* __restrict__ slot, int mode)
{
    const int n = blockIdx.x;
    const int lane = threadIdx.x;
    const float* xr = x + (size_t)n * D_;

    float acc[E_];
#pragma unroll
    for (int e = 0; e < E_; ++e) acc[e] = 0.f;

    for (int d = lane; d < D_; d += 64) {
        const float xv = xr[d];
#pragma unroll
        for (int e = 0; e < E_; ++e)
            acc[e] += xv * Wr[d * E_ + e];
    }
#pragma unroll
    for (int e = 0; e < E_; ++e) {
        float v = acc[e];
#pragma unroll
        for (int off = 32; off > 0; off >>= 1)
            v += __shfl_down(v, off, 64);
        acc[e] = v;
    }
    if (lane == 0) {
        float m = acc[0];
#pragma unroll
        for (int e = 1; e < E_; ++e) m = fmaxf(m, acc[e]);
        float p[E_];
#pragma unroll
        for (int e = 0; e < E_; ++e) p[e] = __expf(acc[e] - m);
        int i0 = 0; float v0 = p[0];
#pragma unroll
        for (int e = 1; e < E_; ++e) if (p[e] > v0) { v0 = p[e]; i0 = e; }
        int i1 = (i0 == 0) ? 1 : 0; float v1 = p[i1];
#pragma unroll
        for (int e = 0; e < E_; ++e) {
            if (e == i0) continue;
            if (p[e] > v1) { v1 = p[e]; i1 = e; }
        }
        const float inv = 1.f / (v0 + v1);
        const float w0 = v0 * inv, w1 = v1 * inv;
        top_idx[n * TOPK + 0] = i0;
        top_idx[n * TOPK + 1] = i1;
        top_w[n * TOPK + 0] = w0;
        top_w[n * TOPK + 1] = w1;
        if (mode & 1) {
            int p0 = atomicAdd(&cnt[i0], 1);
            list[i0 * NTOK + p0] = n;  wgt[i0 * NTOK + p0] = w0;
            int p1 = atomicAdd(&cnt[i1], 1);
            list[i1 * NTOK + p1] = n;  wgt[i1 * NTOK + p1] = w1;
            if (mode & 2) {
                slot[n * TOPK + 0] = (i0 << 16) | p0;
                slot[n * TOPK + 1] = (i1 << 16) | p1;
            }
        }
    }
}

__global__ void prefix_kernel(const int* __restrict__ cnt, int* __restrict__ base)
{
    if (threadIdx.x == 0 && blockIdx.x == 0) {
        int s = 0;
#pragma unroll
        for (int e = 0; e < E_; ++e) { base[e] = s; s += cnt[e]; }
    }
}

// ---------------------------------------------------------------------------
// f32 -> bf16 cast of x
// ---------------------------------------------------------------------------
__global__ __launch_bounds__(256) void convert_x_kernel(
    const float* __restrict__ x, bf16_t* __restrict__ xb)
{
    const int i = blockIdx.x * 256 + threadIdx.x;
    const float4 v = ((const float4*)x)[i];
    uint2 o;
    o.x = (unsigned int)f2bf_rne(v.x) | ((unsigned int)f2bf_rne(v.y) << 16);
    o.y = (unsigned int)f2bf_rne(v.z) | ((unsigned int)f2bf_rne(v.w) << 16);
    ((uint2*)xb)[i] = o;
}

// ---------------------------------------------------------------------------
// Batched transpose: src f32 [Z][R][C] -> dst bf16 [Z][C][R], 64x64 tiles.
// float4 global loads (16 B/lane); [64][65] keeps both LDS phases ~2-way.
// ---------------------------------------------------------------------------
__global__ __launch_bounds__(256) void transpose_kernel(
    const float* __restrict__ src, bf16_t* __restrict__ dst, int R, int C)
{
    __shared__ float tile[64][65];
    const int z  = blockIdx.z;
    const int r0 = blockIdx.y * 64;
    const int c0 = blockIdx.x * 64;
    const float* s = src + (size_t)z * R * C;
    bf16_t*      d = dst + (size_t)z * R * C;
#pragma unroll
    for (int i = 0; i < 4; ++i) {
        const int r  = i * 16 + (threadIdx.x >> 4);
        const int c4 = (threadIdx.x & 15) * 4;
        const float4 v = *(const float4*)(s + (size_t)(r0 + r) * C + c0 + c4);
        tile[r][c4]     = v.x;
        tile[r][c4 + 1] = v.y;
        tile[r][c4 + 2] = v.z;
        tile[r][c4 + 3] = v.w;
    }
    __syncthreads();
    const int rc = (threadIdx.x & 15) * 4;
    const int cc = threadIdx.x >> 4;   // 0..15
#pragma unroll
    for (int i = 0; i < 4; ++i) {
        const int c = i * 16 + cc;
        uint2 o;
        o.x = (unsigned int)f2bf_rne(tile[rc    ][c]) | ((unsigned int)f2bf_rne(tile[rc + 1][c]) << 16);
        o.y = (unsigned int)f2bf_rne(tile[rc + 2][c]) | ((unsigned int)f2bf_rne(tile[rc + 3][c]) << 16);
        *(uint2*)(d + (size_t)(c0 + c) * R + r0 + rc) = o;
    }
}

// ---------------------------------------------------------------------------
// Grouped MFMA GEMM, 256x256 tile, BK=32, 512 threads (8 waves, 2Mx4N).
// 3-deep LDS ring, staging 2 tiles ahead via global_load_lds; counted
// s_waitcnt vmcnt(4) at tile boundaries (never 0 in steady state) so loads
// stay in flight across barriers (T3/T4). LDS chunk XOR-swizzle
// c' = c ^ ((row>>1)&3) applied on pre-swizzled GLOBAL source (gld16 writes
// linearly) and on fragment reads -> <=2-way bank conflicts (free).
// setprio(1) around the 32-MFMA cluster (T5).
// Ring-race audit: write buf (t+2)%3 vs read buf t%3 always disjoint; the
// overwrite of (t+2)%3 (read last at iter t-1) is ordered by the iter t-1
// barrier (all ds_reads complete pre-barrier via lgkm waits before MFMA);
// sched_barrier(0) after each s_barrier blocks read-hoist into the gap.
//
// G==1: A = Xb rows gathered via list, B = W1T[e] (F x D), epilogue
//       gelu(acc+b1) -> H (bf16).
// G==2: A = H rows (be+p), B = W2T[e] (D x F), split-K slab s of kslabs,
//       epilogue acc (+b2 on slab 0) -> Y[s] (f32).
// Requires nk >= 3 (here nk is 32 or 64).
// ---------------------------------------------------------------------------
template<int G>
__global__ __launch_bounds__(512, 2) void mg8_kernel(
    const bf16_t* __restrict__ Amat, const bf16_t* __restrict__ Bmat,
    const float* __restrict__ bias,
    const int* __restrict__ cnt, const int* __restrict__ base,
    const int* __restrict__ list,
    bf16_t* __restrict__ Hout, float* __restrict__ Yout)
{
    __shared__ __align__(16) bf16_t sm[3 * 16384];   // 96 KiB: 3 x (A 16KB + B 16KB)

    const int e  = (G == 1) ? blockIdx.z : (blockIdx.z % E_);
    const int ce = cnt[e];
    const int m0 = blockIdx.y * 256;
    if (m0 >= ce) return;
    const int n0 = blockIdx.x * 256;
    const int be = base[e];

    const int Kfull = (G == 1) ? D_ : F_;
    int klen, kbase, slab;
    if (G == 1) { klen = D_; kbase = 0; slab = 0; }
    else {
        const int kslabs = gridDim.z / E_;
        slab  = blockIdx.z / E_;
        klen  = F_ / kslabs;
        kbase = slab * klen;
    }
    const int nk = klen / 32;

    const int tid  = threadIdx.x;
    const int lane = tid & 63, wave = tid >> 6;
    const int l16 = lane & 15, quad = lane >> 4;
    const int wm = wave >> 2, wn = wave & 3;

    // ---- staging (rows srow, srow+128; pre-swizzled 16B chunk) ----
    const int srow = wave * 16 + (lane >> 2);          // 0..127
    const int sgc  = (lane & 3) ^ ((srow >> 1) & 3);   // involution; same for srow+128
    int rA0 = m0 + srow;        if (rA0 >= ce) rA0 = ce - 1;
    int rA1 = m0 + srow + 128;  if (rA1 >= ce) rA1 = ce - 1;
    const bf16_t *gA0, *gA1;
    if (G == 1) {
        gA0 = Amat + (size_t)list[e * NTOK + rA0] * D_ + sgc * 8;
        gA1 = Amat + (size_t)list[e * NTOK + rA1] * D_ + sgc * 8;
    } else {
        gA0 = Amat + (size_t)(be + rA0) * F_ + kbase + sgc * 8;
        gA1 = Amat + (size_t)(be + rA1) * F_ + kbase + sgc * 8;
    }
    const bf16_t* Be  = Bmat + (size_t)e * F_ * D_;     // same total size both ways
    const bf16_t* gB0 = Be + (size_t)(n0 + srow) * Kfull + kbase + sgc * 8;
    const bf16_t* gB1 = Be + (size_t)(n0 + srow + 128) * Kfull + kbase + sgc * 8;

#define STG(bb, kk) do { \
        bf16_t* la = sm + (bb) * 16384 + wave * 512; \
        bf16_t* lb = la + 8192; \
        gld16(gA0 + (kk), la); \
        gld16(gA1 + (kk), la + 4096); \
        gld16(gB0 + (kk), lb); \
        gld16(gB1 + (kk), lb + 4096); } while (0)

    // ---- fragment read offsets (elems), swizzle folded in ----
    const int swz  = (quad ^ ((l16 >> 1) & 3)) * 8;
    const int aoff = (wm * 128 + l16) * 32 + swz;
    const int boff = 8192 + (wn * 64 + l16) * 32 + swz;

    f32x4 acc[8][4] = {};

    STG(0, 0);
    STG(1, 32);
    asm volatile("s_waitcnt vmcnt(4)" ::: "memory");   // tile 0 landed (all waves after barrier)
    __builtin_amdgcn_s_barrier();
    __builtin_amdgcn_sched_barrier(0);

    int rb = 0;
    for (int t = 0; t < nk; ++t) {
        if (t + 2 < nk) {
            int wb = rb + 2; if (wb >= 3) wb -= 3;
            STG(wb, (t + 2) * 32);
        }
        const bf16_t* bp = sm + rb * 16384;
        i32x4 af[8], bv[4];
#pragma unroll
        for (int m = 0; m < 8; ++m)
            af[m] = *(const i32x4*)(bp + aoff + m * 512);
#pragma unroll
        for (int n = 0; n < 4; ++n)
            bv[n] = *(const i32x4*)(bp + boff + n * 512);
        __builtin_amdgcn_s_setprio(1);
#pragma unroll
        for (int m = 0; m < 8; ++m)
#pragma unroll
            for (int n = 0; n < 4; ++n)
                mfma16(af[m], bv[n], acc[m][n]);
        __builtin_amdgcn_s_setprio(0);
        if (t + 1 < nk) {
            if (t + 2 < nk) asm volatile("s_waitcnt vmcnt(4)" ::: "memory"); // tile t+1 ready
            else            asm volatile("s_waitcnt vmcnt(0)" ::: "memory"); // epilogue drain
            __builtin_amdgcn_s_barrier();
            __builtin_amdgcn_sched_barrier(0);
        }
        rb = (rb == 2) ? 0 : rb + 1;
    }
#undef STG
    asm volatile("s_nop 7\n\ts_nop 7");

    if (G == 1) {
        const float* b1e = bias + (size_t)e * F_;
#pragma unroll
        for (int n = 0; n < 4; ++n) {
            const int col = n0 + wn * 64 + n * 16 + l16;
            const float bb = b1e[col];
#pragma unroll
            for (int m = 0; m < 8; ++m) {
                const int pr = m0 + wm * 128 + m * 16 + quad * 4;
#pragma unroll
                for (int r = 0; r < 4; ++r) {
                    const int p = pr + r;
                    if (p < ce)
                        Hout[(size_t)(be + p) * F_ + col] =
                            f2bf_rne(gelu_exact(acc[m][n][r] + bb));
                }
            }
        }
    } else {
        float* Ys = Yout + (size_t)slab * NROW * D_;
        const float* b2e = bias + (size_t)e * D_;
#pragma unroll
        for (int n = 0; n < 4; ++n) {
            const int col = n0 + wn * 64 + n * 16 + l16;
            const float bb = (slab == 0) ? b2e[col] : 0.f;
#pragma unroll
            for (int m = 0; m < 8; ++m) {
                const int pr = m0 + wm * 128 + m * 16 + quad * 4;
#pragma unroll
                for (int r = 0; r < 4; ++r) {
                    const int p = pr + r;
                    if (p < ce)
                        Ys[(size_t)(be + p) * D_ + col] = acc[m][n][r] + bb;
                }
            }
        }
    }
}

// ---------------------------------------------------------------------------
// Combine: out[n] = sum_k w_k * (sum_s Y_s[row_k])
// ---------------------------------------------------------------------------
__global__ __launch_bounds__(256) void combine_kernel(
    const float* __restrict__ Y, const int* __restrict__ slot,
    const float* __restrict__ tw, const int* __restrict__ base,
    float* __restrict__ out, int kslabs)
{
    const int n = blockIdx.x;
    const int t = threadIdx.x;
    const int s0 = slot[n * TOPK + 0], s1 = slot[n * TOPK + 1];
    const float w0 = tw[n * TOPK + 0], w1 = tw[n * TOPK + 1];
    const int r0 = base[s0 >> 16] + (s0 & 0xffff);
    const int r1 = base[s1 >> 16] + (s1 & 0xffff);
    float4 y0 = ((const float4*)(Y + (size_t)r0 * D_))[t];
    float4 y1 = ((const float4*)(Y + (size_t)r1 * D_))[t];
    if (kslabs == 2) {
        const float* Y1 = Y + (size_t)NROW * D_;
        const float4 a = ((const float4*)(Y1 + (size_t)r0 * D_))[t];
        const float4 b = ((const float4*)(Y1 + (size_t)r1 * D_))[t];
        y0.x += a.x; y0.y += a.y; y0.z += a.z; y0.w += a.w;
        y1.x += b.x; y1.y += b.y; y1.z += b.z; y1.w += b.w;
    }
    float4 o;
    o.x = w0 * y0.x + w1 * y1.x;
    o.y = w0 * y0.y + w1 * y1.y;
    o.z = w0 * y0.z + w1 * y1.z;
    o.w = w0 * y0.w + w1 * y1.w;
    ((float4*)(out + (size_t)n * D_))[t] = o;
}

// ===========================================================================
// Fallback paths (round-2 proven kernels)
// ===========================================================================
#define BM 128
#define BN 128
#define BK 16

__global__ __launch_bounds__(256) void gemm1_kernel(
    const float* __restrict__ x, const float* __restrict__ W1,
    const float* __restrict__ b1,
    const int* __restrict__ cnt, const int* __restrict__ base,
    const int* __restrict__ list, bf16_t* __restrict__ H)
{
    __shared__ __align__(16) float Xs[BK][BM + 4];
    __shared__ __align__(16) float Ws[BK][BN + 4];

    const int e  = blockIdx.z;
    const int ce = cnt[e];
    const int m0 = blockIdx.y * BM;
    if (m0 >= ce) return;
    const int n0 = blockIdx.x * BN;
    const int be = base[e];
    const int t  = threadIdx.x;
    const int tx = t & 15, ty = t >> 4;

    const int xr_row = t >> 1;
    const int xr_c0  = (t & 1) * 8;
    const int p_x    = m0 + xr_row;
    const float* xrow = (p_x < ce) ? (x + (size_t)list[e * NTOK + p_x] * D_) : nullptr;
    const int wr_kk = t >> 4;
    const int wr_c0 = (t & 15) * 8;
    const float* W1e = W1 + (size_t)e * D_ * F_;

    float acc[8][8];
#pragma unroll
    for (int i = 0; i < 8; ++i)
#pragma unroll
        for (int j = 0; j < 8; ++j) acc[i][j] = 0.f;

    for (int k0 = 0; k0 < D_; k0 += BK) {
        float xv[8];
        if (xrow) {
            const float4 a = *(const float4*)(xrow + k0 + xr_c0);
            const float4 b = *(const float4*)(xrow + k0 + xr_c0 + 4);
            xv[0]=a.x; xv[1]=a.y; xv[2]=a.z; xv[3]=a.w;
            xv[4]=b.x; xv[5]=b.y; xv[6]=b.z; xv[7]=b.w;
        } else {
#pragma unroll
            for (int j = 0; j < 8; ++j) xv[j] = 0.f;
        }
#pragma unroll
        for (int j = 0; j < 8; ++j) Xs[xr_c0 + j][xr_row] = xv[j];
        {
            const float* wr = W1e + (size_t)(k0 + wr_kk) * F_ + (n0 + wr_c0);
            *(float4*)&Ws[wr_kk][wr_c0]     = *(const float4*)(wr);
            *(float4*)&Ws[wr_kk][wr_c0 + 4] = *(const float4*)(wr + 4);
        }
        __syncthreads();
#pragma unroll 4
        for (int kk = 0; kk < BK; ++kk) {
            float a[8], b[8];
            *(float4*)&a[0] = *(const float4*)&Xs[kk][ty * 8];
            *(float4*)&a[4] = *(const float4*)&Xs[kk][ty * 8 + 4];
            *(float4*)&b[0] = *(const float4*)&Ws[kk][tx * 8];
            *(float4*)&b[4] = *(const float4*)&Ws[kk][tx * 8 + 4];
#pragma unroll
            for (int i = 0; i < 8; ++i)
#pragma unroll
                for (int j = 0; j < 8; ++j)
                    acc[i][j] += a[i] * b[j];
        }
        __syncthreads();
    }

    const float* b1e = b1 + (size_t)e * F_;
    float bb[8];
#pragma unroll
    for (int j = 0; j < 8; ++j) bb[j] = b1e[n0 + tx * 8 + j];
#pragma unroll
    for (int i = 0; i < 8; ++i) {
        const int p = m0 + ty * 8 + i;
        if (p >= ce) continue;
        unsigned int pk[4];
#pragma unroll
        for (int jj = 0; jj < 4; ++jj) {
            const float g0 = gelu_exact(acc[i][2 * jj]     + bb[2 * jj]);
            const float g1 = gelu_exact(acc[i][2 * jj + 1] + bb[2 * jj + 1]);
            pk[jj] = (unsigned int)f2bf_rne(g0) | ((unsigned int)f2bf_rne(g1) << 16);
        }
        uint4 v; v.x = pk[0]; v.y = pk[1]; v.z = pk[2]; v.w = pk[3];
        *(uint4*)(H + (size_t)(be + p) * F_ + n0 + tx * 8) = v;
    }
}

__global__ __launch_bounds__(256) void gemm2_kernel(
    const bf16_t* __restrict__ H, const float* __restrict__ W2,
    const float* __restrict__ b2,
    const int* __restrict__ cnt, const int* __restrict__ base,
    const int* __restrict__ list, const float* __restrict__ wgt,
    float* __restrict__ out)
{
    __shared__ __align__(16) float Hs[BK][BM + 4];
    __shared__ __align__(16) float Ws[BK][BN + 4];

    const int e  = blockIdx.z;
    const int ce = cnt[e];
    const int m0 = blockIdx.y * BM;
    if (m0 >= ce) return;
    const int n0 = blockIdx.x * BN;
    const int be = base[e];
    const int t  = threadIdx.x;
    const int tx = t & 15, ty = t >> 4;

    const int hr_row = t >> 1;
    const int hr_c0  = (t & 1) * 8;
    const int p_h    = m0 + hr_row;
    const bf16_t* hrow = (p_h < ce) ? (H + (size_t)(be + p_h) * F_) : nullptr;
    const int wr_kk = t >> 4;
    const int wr_c0 = (t & 15) * 8;
    const float* W2e = W2 + (size_t)e * F_ * D_;

    float acc[8][8];
#pragma unroll
    for (int i = 0; i < 8; ++i)
#pragma unroll
        for (int j = 0; j < 8; ++j) acc[i][j] = 0.f;

    for (int k0 = 0; k0 < F_; k0 += BK) {
        float hv[8];
        if (hrow) {
            const uint4 u = *(const uint4*)(hrow + k0 + hr_c0);
            hv[0] = bf2f(u.x & 0xffffu); hv[1] = bf2f(u.x >> 16);
            hv[2] = bf2f(u.y & 0xffffu); hv[3] = bf2f(u.y >> 16);
            hv[4] = bf2f(u.z & 0xffffu); hv[5] = bf2f(u.z >> 16);
            hv[6] = bf2f(u.w & 0xffffu); hv[7] = bf2f(u.w >> 16);
        } else {
#pragma unroll
            for (int j = 0; j < 8; ++j) hv[j] = 0.f;
        }
#pragma unroll
        for (int j = 0; j < 8; ++j) Hs[hr_c0 + j][hr_row] = hv[j];
        {
            const float* wr = W2e + (size_t)(k0 + wr_kk) * D_ + (n0 + wr_c0);
            *(float4*)&Ws[wr_kk][wr_c0]     = *(const float4*)(wr);
            *(float4*)&Ws[wr_kk][wr_c0 + 4] = *(const float4*)(wr + 4);
        }
        __syncthreads();
#pragma unroll 4
        for (int kk = 0; kk < BK; ++kk) {
            float a[8], b[8];
            *(float4*)&a[0] = *(const float4*)&Hs[kk][ty * 8];
            *(float4*)&a[4] = *(const float4*)&Hs[kk][ty * 8 + 4];
            *(float4*)&b[0] = *(const float4*)&Ws[kk][tx * 8];
            *(float4*)&b[4] = *(const float4*)&Ws[kk][tx * 8 + 4];
#pragma unroll
            for (int i = 0; i < 8; ++i)
#pragma unroll
                for (int j = 0; j < 8; ++j)
                    acc[i][j] += a[i] * b[j];
        }
        __syncthreads();
    }

    const float* b2e = b2 + (size_t)e * D_;
    float bb[8];
#pragma unroll
    for (int j = 0; j < 8; ++j) bb[j] = b2e[n0 + tx * 8 + j];
#pragma unroll
    for (int i = 0; i < 8; ++i) {
        const int p = m0 + ty * 8 + i;
        if (p >= ce) continue;
        const int   n = list[e * NTOK + p];
        const float w = wgt[e * NTOK + p];
        float* op = out + (size_t)n * D_ + n0 + tx * 8;
#pragma unroll
        for (int j = 0; j < 8; ++j)
            atomicAdd(&op[j], w * (acc[i][j] + bb[j]));
    }
}

__global__ __launch_bounds__(256) void fallback_expert_kernel(
    const float* __restrict__ x,
    const float* __restrict__ W1, const float* __restrict__ b1,
    const float* __restrict__ W2, const float* __restrict__ b2,
    const int* __restrict__ top_idx, const float* __restrict__ top_w,
    float* __restrict__ out)
{
    __shared__ float x_lds[D_];
    __shared__ float h_lds[F_];

    const int n = blockIdx.x;
    const int t = threadIdx.x;

    ((float4*)x_lds)[t] = ((const float4*)(x + (size_t)n * D_))[t];
    __syncthreads();

    const int d0 = t * 4;
    float acc_out[4] = {0.f, 0.f, 0.f, 0.f};

    for (int k = 0; k < TOPK; ++k) {
        const int   e = top_idx[n * TOPK + k];
        const float w = top_w[n * TOPK + k];
        const float* W1e = W1 + (size_t)e * D_ * F_;
        const float* b1e = b1 + (size_t)e * F_;
#pragma unroll
        for (int tile = 0; tile < 2; ++tile) {
            const int base_f = tile * 2048 + t * 8;
            float a[8];
#pragma unroll
            for (int j = 0; j < 8; ++j) a[j] = b1e[base_f + j];
            const float4* wp = (const float4*)(W1e + base_f);
            for (int d = 0; d < D_; ++d) {
                const float4 w0 = wp[(size_t)d * (F_ / 4)];
                const float4 w1 = wp[(size_t)d * (F_ / 4) + 1];
                const float xv = x_lds[d];
                a[0] += xv * w0.x; a[1] += xv * w0.y;
                a[2] += xv * w0.z; a[3] += xv * w0.w;
                a[4] += xv * w1.x; a[5] += xv * w1.y;
                a[6] += xv * w1.z; a[7] += xv * w1.w;
            }
#pragma unroll
            for (int j = 0; j < 8; ++j)
                h_lds[base_f + j] = gelu_exact(a[j]);
        }
        __syncthreads();

        const float* W2e = W2 + (size_t)e * F_ * D_;
        const float* b2e = b2 + (size_t)e * D_;
        float y[4];
#pragma unroll
        for (int j = 0; j < 4; ++j) y[j] = b2e[d0 + j];
        const float4* wp2 = (const float4*)(W2e + d0);
        for (int f = 0; f < F_; ++f) {
            const float4 wv = wp2[(size_t)f * (D_ / 4)];
            const float hv = h_lds[f];
            y[0] += hv * wv.x; y[1] += hv * wv.y;
            y[2] += hv * wv.z; y[3] += hv * wv.w;
        }
#pragma unroll
        for (int j = 0; j < 4; ++j) acc_out[j] += w * y[j];
        __syncthreads();
    }

    float4 o; o.x = acc_out[0]; o.y = acc_out[1]; o.z = acc_out[2]; o.w = acc_out[3];
    *(float4*)(out + (size_t)n * D_ + d0) = o;
}

extern "C" void kernel_launch(void* const* d_in, const int* in_sizes, int n_in,
                              void* d_out, int out_size, void* d_ws, size_t ws_size,
                              hipStream_t stream) {
    const float* x  = (const float*)d_in[0];
    const float* Wr = (const float*)d_in[1];
    const float* W1 = (const float*)d_in[2];
    const float* b1 = (const float*)d_in[3];
    const float* W2 = (const float*)d_in[4];
    const float* b2 = (const float*)d_in[5];
    float* out = (float*)d_out;

    char* ws = (char*)d_ws;
    int*    cnt   = (int*)(ws + OFF_CNT);
    int*    basep = (int*)(ws + OFF_BASE);
    int*    tidx  = (int*)(ws + OFF_TIDX);
    float*  tw    = (float*)(ws + OFF_TW);
    int*    list  = (int*)(ws + OFF_LIST);
    float*  wgt   = (float*)(ws + OFF_WGT);

    if (ws_size >= WS_MFMA) {
        const int kslabs = (ws_size >= WS_MFMA2) ? 2 : 1;
        int*    slot = (int*)(ws + OFF_SLOT);
        bf16_t* Xb   = (bf16_t*)(ws + OFF_XB);
        bf16_t* W1T  = (bf16_t*)(ws + OFF_W1T);
        bf16_t* W2T  = (bf16_t*)(ws + OFF_W2T);
        bf16_t* H    = (bf16_t*)(ws + OFF_HN);
        float*  Y    = (float*)(ws + OFF_Y);

        hipMemsetAsync(cnt, 0, E_ * sizeof(int), stream);
        router_kernel<<<NTOK, 64, 0, stream>>>(x, Wr, tidx, tw, cnt, list, wgt, slot, 3);
        prefix_kernel<<<1, 64, 0, stream>>>(cnt, basep);
        convert_x_kernel<<<NTOK * D_ / 4 / 256, 256, 0, stream>>>(x, Xb);
        transpose_kernel<<<dim3(F_ / 64, D_ / 64, E_), 256, 0, stream>>>(W1, W1T, D_, F_);
        transpose_kernel<<<dim3(D_ / 64, F_ / 64, E_), 256, 0, stream>>>(W2, W2T, F_, D_);
        mg8_kernel<1><<<dim3(F_ / 256, NTOK / 256, E_), 512, 0, stream>>>(
            Xb, W1T, b1, cnt, basep, list, H, nullptr);
        mg8_kernel<2><<<dim3(D_ / 256, NTOK / 256, E_ * kslabs), 512, 0, stream>>>(
            H, W2T, b2, cnt, basep, nullptr, nullptr, Y);
        combine_kernel<<<NTOK, 256, 0, stream>>>(Y, slot, tw, basep, out, kslabs);
    } else if (ws_size >= WS_OLD) {
        bf16_t* H = (bf16_t*)(ws + OFF_H_OLD);
        hipMemsetAsync(cnt, 0, E_ * sizeof(int), stream);
        router_kernel<<<NTOK, 64, 0, stream>>>(x, Wr, tidx, tw, cnt, list, wgt, nullptr, 1);
        prefix_kernel<<<1, 64, 0, stream>>>(cnt, basep);
        hipMemsetAsync(out, 0, (size_t)NTOK * D_ * sizeof(float), stream);
        gemm1_kernel<<<dim3(F_ / BN, NTOK / BM, E_), 256, 0, stream>>>(
            x, W1, b1, cnt, basep, list, H);
        gemm2_kernel<<<dim3(D_ / BN, NTOK / BM, E_), 256, 0, stream>>>(
            H, W2, b2, cnt, basep, list, wgt, out);
    } else {
        router_kernel<<<NTOK, 64, 0, stream>>>(x, Wr, tidx, tw, cnt, list, wgt, nullptr, 0);
        fallback_expert_kernel<<<NTOK, 256, 0, stream>>>(
            x, W1, b1, W2, b2, tidx, tw, out);
    }
}

// Round 4
// 736.148 us; speedup vs baseline: 1.0007x; 1.0007x over previous
//
#include <hip/hip_runtime.h>
#include <hip/hip_bf16.h>
#include <math.h>

#define B_  2
#define T_  2048
#define D_  1024
#define F_  4096
#define E_  8
#define NTOK 4096       // B_*T_
#define TOPK 2
#define NROW 8192       // NTOK*TOPK total selected rows

typedef unsigned short bf16_t;
typedef float f32x4 __attribute__((ext_vector_type(4)));
typedef int   i32x4 __attribute__((ext_vector_type(4)));
typedef __bf16 bf16x8 __attribute__((ext_vector_type(8)));

// ---- ws layout (bytes) ----
#define OFF_CNT   0                          // int[8]
#define OFF_BASE  32                         // int[8]
#define OFF_TIDX  64                         // int[NTOK*2]
#define OFF_TW    32832                      // float[NTOK*2]
#define OFF_LIST  65600                      // int[8*4096]
#define OFF_WGT   196672                     // float[8*4096]
// old (round-2) path
#define OFF_H_OLD 327744                     // bf16[8192*4096] = 64 MB
#define WS_OLD    (OFF_H_OLD + (size_t)NROW * F_ * 2)
// MFMA path
#define OFF_SLOT  327744                     // int[NTOK*2]  (e<<16 | pos)
#define OFF_XB    (1u << 20)                 // bf16[NTOK*D]      8 MB
#define OFF_W1T   (OFF_XB  + (size_t)NTOK * D_ * 2)         // bf16[E*F*D] 64 MB
#define OFF_W2T   (OFF_W1T + (size_t)E_ * F_ * D_ * 2)      // bf16[E*D*F] 64 MB
#define OFF_HN    (OFF_W2T + (size_t)E_ * D_ * F_ * 2)      // bf16[NROW*F] 64 MB
#define OFF_Y     (OFF_HN  + (size_t)NROW * F_ * 2)         // f32[NROW*D] per slab
#define WS_MFMA   (OFF_Y + (size_t)NROW * D_ * 4)           // 1 slab
#define WS_MFMA2  (OFF_Y + 2 * (size_t)NROW * D_ * 4)       // 2 slabs

__device__ __forceinline__ float gelu_exact(float v) {
    return 0.5f * v * (1.0f + erff(v * 0.70710678118654752440f));
}

__device__ __forceinline__ unsigned short f2bf_rne(float f) {
    union { float f; unsigned int u; } v; v.f = f;
    unsigned int r = (v.u + 0x7fffu + ((v.u >> 16) & 1u)) >> 16;
    return (unsigned short)r;
}

__device__ __forceinline__ float bf2f(unsigned int u) {
    union { unsigned int i; float f; } v; v.i = u << 16; return v.f;
}

// async 16B/lane global->LDS; lds base wave-uniform (+lane*16 implicit)
__device__ __forceinline__ void gld16(const void* g, void* l) {
    __builtin_amdgcn_global_load_lds(
        (const __attribute__((address_space(1))) unsigned int*)g,
        (__attribute__((address_space(3))) unsigned int*)l, 16, 0, 0);
}

// MFMA via compiler intrinsic: SSA-visible, so the allocator feeds the
// accumulator to the MFMA directly (VGPR or AGPR C/D, gfx950 unified RF)
// with NO per-MFMA accvgpr_read/write bounce. Round-2 profile showed the
// "+v" inline-asm form bounced acc through AGPRs around every MFMA
// (VGPR_Count=96 with 128 acc floats; VALUBusy 27%, MfmaUtil 17%).
__device__ __forceinline__ void mfma16(const i32x4& a, const i32x4& b, f32x4& c) {
    c = __builtin_amdgcn_mfma_f32_16x16x32_bf16(
        __builtin_bit_cast(bf16x8, a), __builtin_bit_cast(bf16x8, b), c, 0, 0, 0);
}

// ---------------------------------------------------------------------------
// Router
// ---------------------------------------------------------------------------
__global__ __launch_bounds__(64) void router_kernel(
    const float* __restrict__ x, const float* __restrict__ Wr,
    int* __restrict__ top_idx, float* __restrict__ top_w,
    int* __restrict__ cnt, int* __restrict__ list, float* __restrict__ wgt,
    int* __restrict__ slot, int mode)
{
    const int n = blockIdx.x;
    const int lane = threadIdx.x;
    const float* xr = x + (size_t)n * D_;

    float acc[E_];
#pragma unroll
    for (int e = 0; e < E_; ++e) acc[e] = 0.f;

    for (int d = lane; d < D_; d += 64) {
        const float xv = xr[d];
#pragma unroll
        for (int e = 0; e < E_; ++e)
            acc[e] += xv * Wr[d * E_ + e];
    }
#pragma unroll
    for (int e = 0; e < E_; ++e) {
        float v = acc[e];
#pragma unroll
        for (int off = 32; off > 0; off >>= 1)
            v += __shfl_down(v, off, 64);
        acc[e] = v;
    }
    if (lane == 0) {
        float m = acc[0];
#pragma unroll
        for (int e = 1; e < E_; ++e) m = fmaxf(m, acc[e]);
        float p[E_];
#pragma unroll
        for (int e = 0; e < E_; ++e) p[e] = __expf(acc[e] - m);
        int i0 = 0; float v0 = p[0];
#pragma unroll
        for (int e = 1; e < E_; ++e) if (p[e] > v0) { v0 = p[e]; i0 = e; }
        int i1 = (i0 == 0) ? 1 : 0; float v1 = p[i1];
#pragma unroll
        for (int e = 0; e < E_; ++e) {
            if (e == i0) continue;
            if (p[e] > v1) { v1 = p[e]; i1 = e; }
        }
        const float inv = 1.f / (v0 + v1);
        const float w0 = v0 * inv, w1 = v1 * inv;
        top_idx[n * TOPK + 0] = i0;
        top_idx[n * TOPK + 1] = i1;
        top_w[n * TOPK + 0] = w0;
        top_w[n * TOPK + 1] = w1;
        if (mode & 1) {
            int p0 = atomicAdd(&cnt[i0], 1);
            list[i0 * NTOK + p0] = n;  wgt[i0 * NTOK + p0] = w0;
            int p1 = atomicAdd(&cnt[i1], 1);
            list[i1 * NTOK + p1] = n;  wgt[i1 * NTOK + p1] = w1;
            if (mode & 2) {
                slot[n * TOPK + 0] = (i0 << 16) | p0;
                slot[n * TOPK + 1] = (i1 << 16) | p1;
            }
        }
    }
}

__global__ void prefix_kernel(const int* __restrict__ cnt, int* __restrict__ base)
{
    if (threadIdx.x == 0 && blockIdx.x == 0) {
        int s = 0;
#pragma unroll
        for (int e = 0; e < E_; ++e) { base[e] = s; s += cnt[e]; }
    }
}

// ---------------------------------------------------------------------------
// f32 -> bf16 cast of x
// ---------------------------------------------------------------------------
__global__ __launch_bounds__(256) void convert_x_kernel(
    const float* __restrict__ x, bf16_t* __restrict__ xb)
{
    const int i = blockIdx.x * 256 + threadIdx.x;
    const float4 v = ((const float4*)x)[i];
    uint2 o;
    o.x = (unsigned int)f2bf_rne(v.x) | ((unsigned int)f2bf_rne(v.y) << 16);
    o.y = (unsigned int)f2bf_rne(v.z) | ((unsigned int)f2bf_rne(v.w) << 16);
    ((uint2*)xb)[i] = o;
}

// ---------------------------------------------------------------------------
// Batched transpose: src f32 [Z][R][C] -> dst bf16 [Z][C][R], 64x64 tiles.
// float4 global loads (16 B/lane); [64][65] keeps both LDS phases ~2-way.
// ---------------------------------------------------------------------------
__global__ __launch_bounds__(256) void transpose_kernel(
    const float* __restrict__ src, bf16_t* __restrict__ dst, int R, int C)
{
    __shared__ float tile[64][65];
    const int z  = blockIdx.z;
    const int r0 = blockIdx.y * 64;
    const int c0 = blockIdx.x * 64;
    const float* s = src + (size_t)z * R * C;
    bf16_t*      d = dst + (size_t)z * R * C;
#pragma unroll
    for (int i = 0; i < 4; ++i) {
        const int r  = i * 16 + (threadIdx.x >> 4);
        const int c4 = (threadIdx.x & 15) * 4;
        const float4 v = *(const float4*)(s + (size_t)(r0 + r) * C + c0 + c4);
        tile[r][c4]     = v.x;
        tile[r][c4 + 1] = v.y;
        tile[r][c4 + 2] = v.z;
        tile[r][c4 + 3] = v.w;
    }
    __syncthreads();
    const int rc = (threadIdx.x & 15) * 4;
    const int cc = threadIdx.x >> 4;   // 0..15
#pragma unroll
    for (int i = 0; i < 4; ++i) {
        const int c = i * 16 + cc;
        uint2 o;
        o.x = (unsigned int)f2bf_rne(tile[rc    ][c]) | ((unsigned int)f2bf_rne(tile[rc + 1][c]) << 16);
        o.y = (unsigned int)f2bf_rne(tile[rc + 2][c]) | ((unsigned int)f2bf_rne(tile[rc + 3][c]) << 16);
        *(uint2*)(d + (size_t)(c0 + c) * R + r0 + rc) = o;
    }
}

// ---------------------------------------------------------------------------
// Grouped MFMA GEMM, 256x256 tile, BK=32, 512 threads (8 waves, 2Mx4N).
// 3-deep LDS ring, staging 2 tiles ahead via global_load_lds; counted
// s_waitcnt vmcnt(4) at tile boundaries (never 0 in steady state) so loads
// stay in flight across barriers (T3/T4). LDS chunk XOR-swizzle
// c' = c ^ ((row>>1)&3) applied on pre-swizzled GLOBAL source (gld16 writes
// linearly) and on fragment reads -> 0 bank conflicts (verified round 2).
// setprio(1) around the 32-MFMA cluster (T5). MFMA via builtin intrinsic
// (no accvgpr bounce).
//
// G==1: A = Xb rows gathered via list, B = W1T[e] (F x D), epilogue
//       gelu(acc+b1) -> H (bf16).
// G==2: A = H rows (be+p), B = W2T[e] (D x F), split-K slab s of kslabs,
//       epilogue acc (+b2 on slab 0) -> Y[s] (f32).
// Requires nk >= 3 (here nk is 32 or 64).
// ---------------------------------------------------------------------------
template<int G>
__global__ __launch_bounds__(512, 2) void mg8_kernel(
    const bf16_t* __restrict__ Amat, const bf16_t* __restrict__ Bmat,
    const float* __restrict__ bias,
    const int* __restrict__ cnt, const int* __restrict__ base,
    const int* __restrict__ list,
    bf16_t* __restrict__ Hout, float* __restrict__ Yout)
{
    __shared__ __align__(16) bf16_t sm[3 * 16384];   // 96 KiB: 3 x (A 16KB + B 16KB)

    const int e  = (G == 1) ? blockIdx.z : (blockIdx.z % E_);
    const int ce = cnt[e];
    const int m0 = blockIdx.y * 256;
    if (m0 >= ce) return;
    const int n0 = blockIdx.x * 256;
    const int be = base[e];

    const int Kfull = (G == 1) ? D_ : F_;
    int klen, kbase, slab;
    if (G == 1) { klen = D_; kbase = 0; slab = 0; }
    else {
        const int kslabs = gridDim.z / E_;
        slab  = blockIdx.z / E_;
        klen  = F_ / kslabs;
        kbase = slab * klen;
    }
    const int nk = klen / 32;

    const int tid  = threadIdx.x;
    const int lane = tid & 63, wave = tid >> 6;
    const int l16 = lane & 15, quad = lane >> 4;
    const int wm = wave >> 2, wn = wave & 3;

    // ---- staging (rows srow, srow+128; pre-swizzled 16B chunk) ----
    const int srow = wave * 16 + (lane >> 2);          // 0..127
    const int sgc  = (lane & 3) ^ ((srow >> 1) & 3);   // involution; same for srow+128
    int rA0 = m0 + srow;        if (rA0 >= ce) rA0 = ce - 1;
    int rA1 = m0 + srow + 128;  if (rA1 >= ce) rA1 = ce - 1;
    const bf16_t *gA0, *gA1;
    if (G == 1) {
        gA0 = Amat + (size_t)list[e * NTOK + rA0] * D_ + sgc * 8;
        gA1 = Amat + (size_t)list[e * NTOK + rA1] * D_ + sgc * 8;
    } else {
        gA0 = Amat + (size_t)(be + rA0) * F_ + kbase + sgc * 8;
        gA1 = Amat + (size_t)(be + rA1) * F_ + kbase + sgc * 8;
    }
    const bf16_t* Be  = Bmat + (size_t)e * F_ * D_;     // same total size both ways
    const bf16_t* gB0 = Be + (size_t)(n0 + srow) * Kfull + kbase + sgc * 8;
    const bf16_t* gB1 = Be + (size_t)(n0 + srow + 128) * Kfull + kbase + sgc * 8;

#define STG(bb, kk) do { \
        bf16_t* la = sm + (bb) * 16384 + wave * 512; \
        bf16_t* lb = la + 8192; \
        gld16(gA0 + (kk), la); \
        gld16(gA1 + (kk), la + 4096); \
        gld16(gB0 + (kk), lb); \
        gld16(gB1 + (kk), lb + 4096); } while (0)

    // ---- fragment read offsets (elems), swizzle folded in ----
    const int swz  = (quad ^ ((l16 >> 1) & 3)) * 8;
    const int aoff = (wm * 128 + l16) * 32 + swz;
    const int boff = 8192 + (wn * 64 + l16) * 32 + swz;

    f32x4 acc[8][4] = {};

    STG(0, 0);
    STG(1, 32);
    asm volatile("s_waitcnt vmcnt(4)" ::: "memory");   // tile 0 landed (all waves after barrier)
    __builtin_amdgcn_s_barrier();
    __builtin_amdgcn_sched_barrier(0);

    int rb = 0;
    for (int t = 0; t < nk; ++t) {
        if (t + 2 < nk) {
            int wb = rb + 2; if (wb >= 3) wb -= 3;
            STG(wb, (t + 2) * 32);
        }
        const bf16_t* bp = sm + rb * 16384;
        i32x4 af[8], bv[4];
#pragma unroll
        for (int m = 0; m < 8; ++m)
            af[m] = *(const i32x4*)(bp + aoff + m * 512);
#pragma unroll
        for (int n = 0; n < 4; ++n)
            bv[n] = *(const i32x4*)(bp + boff + n * 512);
        __builtin_amdgcn_s_setprio(1);
#pragma unroll
        for (int m = 0; m < 8; ++m)
#pragma unroll
            for (int n = 0; n < 4; ++n)
                mfma16(af[m], bv[n], acc[m][n]);
        __builtin_amdgcn_s_setprio(0);
        if (t + 1 < nk) {
            if (t + 2 < nk) asm volatile("s_waitcnt vmcnt(4)" ::: "memory"); // tile t+1 ready
            else            asm volatile("s_waitcnt vmcnt(0)" ::: "memory"); // epilogue drain
            __builtin_amdgcn_s_barrier();
            __builtin_amdgcn_sched_barrier(0);
        }
        rb = (rb == 2) ? 0 : rb + 1;
    }
#undef STG

    if (G == 1) {
        const float* b1e = bias + (size_t)e * F_;
#pragma unroll
        for (int n = 0; n < 4; ++n) {
            const int col = n0 + wn * 64 + n * 16 + l16;
            const float bb = b1e[col];
#pragma unroll
            for (int m = 0; m < 8; ++m) {
                const int pr = m0 + wm * 128 + m * 16 + quad * 4;
#pragma unroll
                for (int r = 0; r < 4; ++r) {
                    const int p = pr + r;
                    if (p < ce)
                        Hout[(size_t)(be + p) * F_ + col] =
                            f2bf_rne(gelu_exact(acc[m][n][r] + bb));
                }
            }
        }
    } else {
        float* Ys = Yout + (size_t)slab * NROW * D_;
        const float* b2e = bias + (size_t)e * D_;
#pragma unroll
        for (int n = 0; n < 4; ++n) {
            const int col = n0 + wn * 64 + n * 16 + l16;
            const float bb = (slab == 0) ? b2e[col] : 0.f;
#pragma unroll
            for (int m = 0; m < 8; ++m) {
                const int pr = m0 + wm * 128 + m * 16 + quad * 4;
#pragma unroll
                for (int r = 0; r < 4; ++r) {
                    const int p = pr + r;
                    if (p < ce)
                        Ys[(size_t)(be + p) * D_ + col] = acc[m][n][r] + bb;
                }
            }
        }
    }
}

// ---------------------------------------------------------------------------
// Combine: out[n] = sum_k w_k * (sum_s Y_s[row_k])
// ---------------------------------------------------------------------------
__global__ __launch_bounds__(256) void combine_kernel(
    const float* __restrict__ Y, const int* __restrict__ slot,
    const float* __restrict__ tw, const int* __restrict__ base,
    float* __restrict__ out, int kslabs)
{
    const int n = blockIdx.x;
    const int t = threadIdx.x;
    const int s0 = slot[n * TOPK + 0], s1 = slot[n * TOPK + 1];
    const float w0 = tw[n * TOPK + 0], w1 = tw[n * TOPK + 1];
    const int r0 = base[s0 >> 16] + (s0 & 0xffff);
    const int r1 = base[s1 >> 16] + (s1 & 0xffff);
    float4 y0 = ((const float4*)(Y + (size_t)r0 * D_))[t];
    float4 y1 = ((const float4*)(Y + (size_t)r1 * D_))[t];
    if (kslabs == 2) {
        const float* Y1 = Y + (size_t)NROW * D_;
        const float4 a = ((const float4*)(Y1 + (size_t)r0 * D_))[t];
        const float4 b = ((const float4*)(Y1 + (size_t)r1 * D_))[t];
        y0.x += a.x; y0.y += a.y; y0.z += a.z; y0.w += a.w;
        y1.x += b.x; y1.y += b.y; y1.z += b.z; y1.w += b.w;
    }
    float4 o;
    o.x = w0 * y0.x + w1 * y1.x;
    o.y = w0 * y0.y + w1 * y1.y;
    o.z = w0 * y0.z + w1 * y1.z;
    o.w = w0 * y0.w + w1 * y1.w;
    ((float4*)(out + (size_t)n * D_))[t] = o;
}

// ===========================================================================
// Fallback paths (round-2 proven kernels)
// ===========================================================================
#define BM 128
#define BN 128
#define BK 16

__global__ __launch_bounds__(256) void gemm1_kernel(
    const float* __restrict__ x, const float* __restrict__ W1,
    const float* __restrict__ b1,
    const int* __restrict__ cnt, const int* __restrict__ base,
    const int* __restrict__ list, bf16_t* __restrict__ H)
{
    __shared__ __align__(16) float Xs[BK][BM + 4];
    __shared__ __align__(16) float Ws[BK][BN + 4];

    const int e  = blockIdx.z;
    const int ce = cnt[e];
    const int m0 = blockIdx.y * BM;
    if (m0 >= ce) return;
    const int n0 = blockIdx.x * BN;
    const int be = base[e];
    const int t  = threadIdx.x;
    const int tx = t & 15, ty = t >> 4;

    const int xr_row = t >> 1;
    const int xr_c0  = (t & 1) * 8;
    const int p_x    = m0 + xr_row;
    const float* xrow = (p_x < ce) ? (x + (size_t)list[e * NTOK + p_x] * D_) : nullptr;
    const int wr_kk = t >> 4;
    const int wr_c0 = (t & 15) * 8;
    const float* W1e = W1 + (size_t)e * D_ * F_;

    float acc[8][8];
#pragma unroll
    for (int i = 0; i < 8; ++i)
#pragma unroll
        for (int j = 0; j < 8; ++j) acc[i][j] = 0.f;

    for (int k0 = 0; k0 < D_; k0 += BK) {
        float xv[8];
        if (xrow) {
            const float4 a = *(const float4*)(xrow + k0 + xr_c0);
            const float4 b = *(const float4*)(xrow + k0 + xr_c0 + 4);
            xv[0]=a.x; xv[1]=a.y; xv[2]=a.z; xv[3]=a.w;
            xv[4]=b.x; xv[5]=b.y; xv[6]=b.z; xv[7]=b.w;
        } else {
#pragma unroll
            for (int j = 0; j < 8; ++j) xv[j] = 0.f;
        }
#pragma unroll
        for (int j = 0; j < 8; ++j) Xs[xr_c0 + j][xr_row] = xv[j];
        {
            const float* wr = W1e + (size_t)(k0 + wr_kk) * F_ + (n0 + wr_c0);
            *(float4*)&Ws[wr_kk][wr_c0]     = *(const float4*)(wr);
            *(float4*)&Ws[wr_kk][wr_c0 + 4] = *(const float4*)(wr + 4);
        }
        __syncthreads();
#pragma unroll 4
        for (int kk = 0; kk < BK; ++kk) {
            float a[8], b[8];
            *(float4*)&a[0] = *(const float4*)&Xs[kk][ty * 8];
            *(float4*)&a[4] = *(const float4*)&Xs[kk][ty * 8 + 4];
            *(float4*)&b[0] = *(const float4*)&Ws[kk][tx * 8];
            *(float4*)&b[4] = *(const float4*)&Ws[kk][tx * 8 + 4];
#pragma unroll
            for (int i = 0; i < 8; ++i)
#pragma unroll
                for (int j = 0; j < 8; ++j)
                    acc[i][j] += a[i] * b[j];
        }
        __syncthreads();
    }

    const float* b1e = b1 + (size_t)e * F_;
    float bb[8];
#pragma unroll
    for (int j = 0; j < 8; ++j) bb[j] = b1e[n0 + tx * 8 + j];
#pragma unroll
    for (int i = 0; i < 8; ++i) {
        const int p = m0 + ty * 8 + i;
        if (p >= ce) continue;
        unsigned int pk[4];
#pragma unroll
        for (int jj = 0; jj < 4; ++jj) {
            const float g0 = gelu_exact(acc[i][2 * jj]     + bb[2 * jj]);
            const float g1 = gelu_exact(acc[i][2 * jj + 1] + bb[2 * jj + 1]);
            pk[jj] = (unsigned int)f2bf_rne(g0) | ((unsigned int)f2bf_rne(g1) << 16);
        }
        uint4 v; v.x = pk[0]; v.y = pk[1]; v.z = pk[2]; v.w = pk[3];
        *(uint4*)(H + (size_t)(be + p) * F_ + n0 + tx * 8) = v;
    }
}

__global__ __launch_bounds__(256) void gemm2_kernel(
    const bf16_t* __restrict__ H, const float* __restrict__ W2,
    const float* __restrict__ b2,
    const int* __restrict__ cnt, const int* __restrict__ base,
    const int* __restrict__ list, const float* __restrict__ wgt,
    float* __restrict__ out)
{
    __shared__ __align__(16) float Hs[BK][BM + 4];
    __shared__ __align__(16) float Ws[BK][BN + 4];

    const int e  = blockIdx.z;
    const int ce = cnt[e];
    const int m0 = blockIdx.y * BM;
    if (m0 >= ce) return;
    const int n0 = blockIdx.x * BN;
    const int be = base[e];
    const int t  = threadIdx.x;
    const int tx = t & 15, ty = t >> 4;

    const int hr_row = t >> 1;
    const int hr_c0  = (t & 1) * 8;
    const int p_h    = m0 + hr_row;
    const bf16_t* hrow = (p_h < ce) ? (H + (size_t)(be + p_h) * F_) : nullptr;
    const int wr_kk = t >> 4;
    const int wr_c0 = (t & 15) * 8;
    const float* W2e = W2 + (size_t)e * F_ * D_;

    float acc[8][8];
#pragma unroll
    for (int i = 0; i < 8; ++i)
#pragma unroll
        for (int j = 0; j < 8; ++j) acc[i][j] = 0.f;

    for (int k0 = 0; k0 < F_; k0 += BK) {
        float hv[8];
        if (hrow) {
            const uint4 u = *(const uint4*)(hrow + k0 + hr_c0);
            hv[0] = bf2f(u.x & 0xffffu); hv[1] = bf2f(u.x >> 16);
            hv[2] = bf2f(u.y & 0xffffu); hv[3] = bf2f(u.y >> 16);
            hv[4] = bf2f(u.z & 0xffffu); hv[5] = bf2f(u.z >> 16);
            hv[6] = bf2f(u.w & 0xffffu); hv[7] = bf2f(u.w >> 16);
        } else {
#pragma unroll
            for (int j = 0; j < 8; ++j) hv[j] = 0.f;
        }
#pragma unroll
        for (int j = 0; j < 8; ++j) Hs[hr_c0 + j][hr_row] = hv[j];
        {
            const float* wr = W2e + (size_t)(k0 + wr_kk) * D_ + (n0 + wr_c0);
            *(float4*)&Ws[wr_kk][wr_c0]     = *(const float4*)(wr);
            *(float4*)&Ws[wr_kk][wr_c0 + 4] = *(const float4*)(wr + 4);
        }
        __syncthreads();
#pragma unroll 4
        for (int kk = 0; kk < BK; ++kk) {
            float a[8], b[8];
            *(float4*)&a[0] = *(const float4*)&Hs[kk][ty * 8];
            *(float4*)&a[4] = *(const float4*)&Hs[kk][ty * 8 + 4];
            *(float4*)&b[0] = *(const float4*)&Ws[kk][tx * 8];
            *(float4*)&b[4] = *(const float4*)&Ws[kk][tx * 8 + 4];
#pragma unroll
            for (int i = 0; i < 8; ++i)
#pragma unroll
                for (int j = 0; j < 8; ++j)
                    acc[i][j] += a[i] * b[j];
        }
        __syncthreads();
    }

    const float* b2e = b2 + (size_t)e * D_;
    float bb[8];
#pragma unroll
    for (int j = 0; j < 8; ++j) bb[j] = b2e[n0 + tx * 8 + j];
#pragma unroll
    for (int i = 0; i < 8; ++i) {
        const int p = m0 + ty * 8 + i;
        if (p >= ce) continue;
        const int   n = list[e * NTOK + p];
        const float w = wgt[e * NTOK + p];
        float* op = out + (size_t)n * D_ + n0 + tx * 8;
#pragma unroll
        for (int j = 0; j < 8; ++j)
            atomicAdd(&op[j], w * (acc[i][j] + bb[j]));
    }
}

__global__ __launch_bounds__(256) void fallback_expert_kernel(
    const float* __restrict__ x,
    const float* __restrict__ W1, const float* __restrict__ b1,
    const float* __restrict__ W2, const float* __restrict__ b2,
    const int* __restrict__ top_idx, const float* __restrict__ top_w,
    float* __restrict__ out)
{
    __shared__ float x_lds[D_];
    __shared__ float h_lds[F_];

    const int n = blockIdx.x;
    const int t = threadIdx.x;

    ((float4*)x_lds)[t] = ((const float4*)(x + (size_t)n * D_))[t];
    __syncthreads();

    const int d0 = t * 4;
    float acc_out[4] = {0.f, 0.f, 0.f, 0.f};

    for (int k = 0; k < TOPK; ++k) {
        const int   e = top_idx[n * TOPK + k];
        const float w = top_w[n * TOPK + k];
        const float* W1e = W1 + (size_t)e * D_ * F_;
        const float* b1e = b1 + (size_t)e * F_;
#pragma unroll
        for (int tile = 0; tile < 2; ++tile) {
            const int base_f = tile * 2048 + t * 8;
            float a[8];
#pragma unroll
            for (int j = 0; j < 8; ++j) a[j] = b1e[base_f + j];
            const float4* wp = (const float4*)(W1e + base_f);
            for (int d = 0; d < D_; ++d) {
                const float4 w0 = wp[(size_t)d * (F_ / 4)];
                const float4 w1 = wp[(size_t)d * (F_ / 4) + 1];
                const float xv = x_lds[d];
                a[0] += xv * w0.x; a[1] += xv * w0.y;
                a[2] += xv * w0.z; a[3] += xv * w0.w;
                a[4] += xv * w1.x; a[5] += xv * w1.y;
                a[6] += xv * w1.z; a[7] += xv * w1.w;
            }
#pragma unroll
            for (int j = 0; j < 8; ++j)
                h_lds[base_f + j] = gelu_exact(a[j]);
        }
        __syncthreads();

        const float* W2e = W2 + (size_t)e * F_ * D_;
        const float* b2e = b2 + (size_t)e * D_;
        float y[4];
#pragma unroll
        for (int j = 0; j < 4; ++j) y[j] = b2e[d0 + j];
        const float4* wp2 = (const float4*)(W2e + d0);
        for (int f = 0; f < F_; ++f) {
            const float4 wv = wp2[(size_t)f * (D_ / 4)];
            const float hv = h_lds[f];
            y[0] += hv * wv.x; y[1] += hv * wv.y;
            y[2] += hv * wv.z; y[3] += hv * wv.w;
        }
#pragma unroll
        for (int j = 0; j < 4; ++j) acc_out[j] += w * y[j];
        __syncthreads();
    }

    float4 o; o.x = acc_out[0]; o.y = acc_out[1]; o.z = acc_out[2]; o.w = acc_out[3];
    *(float4*)(out + (size_t)n * D_ + d0) = o;
}

extern "C" void kernel_launch(void* const* d_in, const int* in_sizes, int n_in,
                              void* d_out, int out_size, void* d_ws, size_t ws_size,
                              hipStream_t stream) {
    const float* x  = (const float*)d_in[0];
    const float* Wr = (const float*)d_in[1];
    const float* W1 = (const float*)d_in[2];
    const float* b1 = (const float*)d_in[3];
    const float* W2 = (const float*)d_in[4];
    const float* b2 = (const float*)d_in[5];
    float* out = (float*)d_out;

    char* ws = (char*)d_ws;
    int*    cnt   = (int*)(ws + OFF_CNT);
    int*    basep = (int*)(ws + OFF_BASE);
    int*    tidx  = (int*)(ws + OFF_TIDX);
    float*  tw    = (float*)(ws + OFF_TW);
    int*    list  = (int*)(ws + OFF_LIST);
    float*  wgt   = (float*)(ws + OFF_WGT);

    if (ws_size >= WS_MFMA) {
        const int kslabs = (ws_size >= WS_MFMA2) ? 2 : 1;
        int*    slot = (int*)(ws + OFF_SLOT);
        bf16_t* Xb   = (bf16_t*)(ws + OFF_XB);
        bf16_t* W1T  = (bf16_t*)(ws + OFF_W1T);
        bf16_t* W2T  = (bf16_t*)(ws + OFF_W2T);
        bf16_t* H    = (bf16_t*)(ws + OFF_HN);
        float*  Y    = (float*)(ws + OFF_Y);

        hipMemsetAsync(cnt, 0, E_ * sizeof(int), stream);
        router_kernel<<<NTOK, 64, 0, stream>>>(x, Wr, tidx, tw, cnt, list, wgt, slot, 3);
        prefix_kernel<<<1, 64, 0, stream>>>(cnt, basep);
        convert_x_kernel<<<NTOK * D_ / 4 / 256, 256, 0, stream>>>(x, Xb);
        transpose_kernel<<<dim3(F_ / 64, D_ / 64, E_), 256, 0, stream>>>(W1, W1T, D_, F_);
        transpose_kernel<<<dim3(D_ / 64, F_ / 64, E_), 256, 0, stream>>>(W2, W2T, F_, D_);
        mg8_kernel<1><<<dim3(F_ / 256, NTOK / 256, E_), 512, 0, stream>>>(
            Xb, W1T, b1, cnt, basep, list, H, nullptr);
        mg8_kernel<2><<<dim3(D_ / 256, NTOK / 256, E_ * kslabs), 512, 0, stream>>>(
            H, W2T, b2, cnt, basep, nullptr, nullptr, Y);
        combine_kernel<<<NTOK, 256, 0, stream>>>(Y, slot, tw, basep, out, kslabs);
    } else if (ws_size >= WS_OLD) {
        bf16_t* H = (bf16_t*)(ws + OFF_H_OLD);
        hipMemsetAsync(cnt, 0, E_ * sizeof(int), stream);
        router_kernel<<<NTOK, 64, 0, stream>>>(x, Wr, tidx, tw, cnt, list, wgt, nullptr, 1);
        prefix_kernel<<<1, 64, 0, stream>>>(cnt, basep);
        hipMemsetAsync(out, 0, (size_t)NTOK * D_ * sizeof(float), stream);
        gemm1_kernel<<<dim3(F_ / BN, NTOK / BM, E_), 256, 0, stream>>>(
            x, W1, b1, cnt, basep, list, H);
        gemm2_kernel<<<dim3(D_ / BN, NTOK / BM, E_), 256, 0, stream>>>(
            H, W2, b2, cnt, basep, list, wgt, out);
    } else {
        router_kernel<<<NTOK, 64, 0, stream>>>(x, Wr, tidx, tw, cnt, list, wgt, nullptr, 0);
        fallback_expert_kernel<<<NTOK, 256, 0, stream>>>(
            x, W1, b1, W2, b2, tidx, tw, out);
    }
}

// Round 5
// 730.686 us; speedup vs baseline: 1.0082x; 1.0075x over previous
//
#include <hip/hip_runtime.h>
#include <hip/hip_bf16.h>
#include <math.h>

#define B_  2
#define T_  2048
#define D_  1024
#define F_  4096
#define E_  8
#define NTOK 4096       // B_*T_
#define TOPK 2
#define NROW 8192       // NTOK*TOPK total selected rows

typedef unsigned short bf16_t;
typedef float f32x4 __attribute__((ext_vector_type(4)));
typedef int   i32x4 __attribute__((ext_vector_type(4)));
typedef __bf16 bf16x8 __attribute__((ext_vector_type(8)));

// ---- ws layout (bytes) ----
#define OFF_CNT   0                          // int[8]
#define OFF_BASE  32                         // int[8]
#define OFF_TIDX  64                         // int[NTOK*2]
#define OFF_TW    32832                      // float[NTOK*2]
#define OFF_LIST  65600                      // int[8*4096]
#define OFF_WGT   196672                     // float[8*4096]
// old (round-2) path
#define OFF_H_OLD 327744                     // bf16[8192*4096] = 64 MB
#define WS_OLD    (OFF_H_OLD + (size_t)NROW * F_ * 2)
// MFMA path
#define OFF_SLOT  327744                     // int[NTOK*2]  (e<<16 | pos)
#define OFF_XB    (1u << 20)                 // bf16[NTOK*D]      8 MB
#define OFF_W1T   (OFF_XB  + (size_t)NTOK * D_ * 2)         // bf16[E*F*D] 64 MB
#define OFF_W2T   (OFF_W1T + (size_t)E_ * F_ * D_ * 2)      // bf16[E*D*F] 64 MB
#define OFF_HN    (OFF_W2T + (size_t)E_ * D_ * F_ * 2)      // bf16[NROW*F] 64 MB
#define OFF_Y     (OFF_HN  + (size_t)NROW * F_ * 2)         // f32[NROW*D] per slab
#define WS_MFMA   (OFF_Y + (size_t)NROW * D_ * 4)           // 1 slab
#define WS_MFMA2  (OFF_Y + 2 * (size_t)NROW * D_ * 4)       // 2 slabs

__device__ __forceinline__ float gelu_exact(float v) {
    return 0.5f * v * (1.0f + erff(v * 0.70710678118654752440f));
}

__device__ __forceinline__ unsigned short f2bf_rne(float f) {
    union { float f; unsigned int u; } v; v.f = f;
    unsigned int r = (v.u + 0x7fffu + ((v.u >> 16) & 1u)) >> 16;
    return (unsigned short)r;
}

__device__ __forceinline__ float bf2f(unsigned int u) {
    union { unsigned int i; float f; } v; v.i = u << 16; return v.f;
}

// async 16B/lane global->LDS; lds base wave-uniform (+lane*16 implicit)
__device__ __forceinline__ void gld16(const void* g, void* l) {
    __builtin_amdgcn_global_load_lds(
        (const __attribute__((address_space(1))) unsigned int*)g,
        (__attribute__((address_space(3))) unsigned int*)l, 16, 0, 0);
}

__device__ __forceinline__ void mfma16(const i32x4& a, const i32x4& b, f32x4& c) {
    c = __builtin_amdgcn_mfma_f32_16x16x32_bf16(
        __builtin_bit_cast(bf16x8, a), __builtin_bit_cast(bf16x8, b), c, 0, 0, 0);
}

// ---------------------------------------------------------------------------
// Router
// ---------------------------------------------------------------------------
__global__ __launch_bounds__(64) void router_kernel(
    const float* __restrict__ x, const float* __restrict__ Wr,
    int* __restrict__ top_idx, float* __restrict__ top_w,
    int* __restrict__ cnt, int* __restrict__ list, float* __restrict__ wgt,
    int* __restrict__ slot, int mode)
{
    const int n = blockIdx.x;
    const int lane = threadIdx.x;
    const float* xr = x + (size_t)n * D_;

    float acc[E_];
#pragma unroll
    for (int e = 0; e < E_; ++e) acc[e] = 0.f;

    for (int d = lane; d < D_; d += 64) {
        const float xv = xr[d];
#pragma unroll
        for (int e = 0; e < E_; ++e)
            acc[e] += xv * Wr[d * E_ + e];
    }
#pragma unroll
    for (int e = 0; e < E_; ++e) {
        float v = acc[e];
#pragma unroll
        for (int off = 32; off > 0; off >>= 1)
            v += __shfl_down(v, off, 64);
        acc[e] = v;
    }
    if (lane == 0) {
        float m = acc[0];
#pragma unroll
        for (int e = 1; e < E_; ++e) m = fmaxf(m, acc[e]);
        float p[E_];
#pragma unroll
        for (int e = 0; e < E_; ++e) p[e] = __expf(acc[e] - m);
        int i0 = 0; float v0 = p[0];
#pragma unroll
        for (int e = 1; e < E_; ++e) if (p[e] > v0) { v0 = p[e]; i0 = e; }
        int i1 = (i0 == 0) ? 1 : 0; float v1 = p[i1];
#pragma unroll
        for (int e = 0; e < E_; ++e) {
            if (e == i0) continue;
            if (p[e] > v1) { v1 = p[e]; i1 = e; }
        }
        const float inv = 1.f / (v0 + v1);
        const float w0 = v0 * inv, w1 = v1 * inv;
        top_idx[n * TOPK + 0] = i0;
        top_idx[n * TOPK + 1] = i1;
        top_w[n * TOPK + 0] = w0;
        top_w[n * TOPK + 1] = w1;
        if (mode & 1) {
            int p0 = atomicAdd(&cnt[i0], 1);
            list[i0 * NTOK + p0] = n;  wgt[i0 * NTOK + p0] = w0;
            int p1 = atomicAdd(&cnt[i1], 1);
            list[i1 * NTOK + p1] = n;  wgt[i1 * NTOK + p1] = w1;
            if (mode & 2) {
                slot[n * TOPK + 0] = (i0 << 16) | p0;
                slot[n * TOPK + 1] = (i1 << 16) | p1;
            }
        }
    }
}

__global__ void prefix_kernel(const int* __restrict__ cnt, int* __restrict__ base)
{
    if (threadIdx.x == 0 && blockIdx.x == 0) {
        int s = 0;
#pragma unroll
        for (int e = 0; e < E_; ++e) { base[e] = s; s += cnt[e]; }
    }
}

// ---------------------------------------------------------------------------
// f32 -> bf16 cast of x
// ---------------------------------------------------------------------------
__global__ __launch_bounds__(256) void convert_x_kernel(
    const float* __restrict__ x, bf16_t* __restrict__ xb)
{
    const int i = blockIdx.x * 256 + threadIdx.x;
    const float4 v = ((const float4*)x)[i];
    uint2 o;
    o.x = (unsigned int)f2bf_rne(v.x) | ((unsigned int)f2bf_rne(v.y) << 16);
    o.y = (unsigned int)f2bf_rne(v.z) | ((unsigned int)f2bf_rne(v.w) << 16);
    ((uint2*)xb)[i] = o;
}

// ---------------------------------------------------------------------------
// Batched transpose: src f32 [Z][R][C] -> dst bf16 [Z][C][R], 64x64 tiles.
// ---------------------------------------------------------------------------
__global__ __launch_bounds__(256) void transpose_kernel(
    const float* __restrict__ src, bf16_t* __restrict__ dst, int R, int C)
{
    __shared__ float tile[64][65];
    const int z  = blockIdx.z;
    const int r0 = blockIdx.y * 64;
    const int c0 = blockIdx.x * 64;
    const float* s = src + (size_t)z * R * C;
    bf16_t*      d = dst + (size_t)z * R * C;
#pragma unroll
    for (int i = 0; i < 4; ++i) {
        const int r  = i * 16 + (threadIdx.x >> 4);
        const int c4 = (threadIdx.x & 15) * 4;
        const float4 v = *(const float4*)(s + (size_t)(r0 + r) * C + c0 + c4);
        tile[r][c4]     = v.x;
        tile[r][c4 + 1] = v.y;
        tile[r][c4 + 2] = v.z;
        tile[r][c4 + 3] = v.w;
    }
    __syncthreads();
    const int rc = (threadIdx.x & 15) * 4;
    const int cc = threadIdx.x >> 4;   // 0..15
#pragma unroll
    for (int i = 0; i < 4; ++i) {
        const int c = i * 16 + cc;
        uint2 o;
        o.x = (unsigned int)f2bf_rne(tile[rc    ][c]) | ((unsigned int)f2bf_rne(tile[rc + 1][c]) << 16);
        o.y = (unsigned int)f2bf_rne(tile[rc + 2][c]) | ((unsigned int)f2bf_rne(tile[rc + 3][c]) << 16);
        *(uint2*)(d + (size_t)(c0 + c) * R + r0 + rc) = o;
    }
}

// ---------------------------------------------------------------------------
// Grouped MFMA GEMM, 256x256 tile, BK=64, 512 threads (8 waves, 2Mx4N).
// PROVEN 2-phase template (T3-minimum, m97/m248 structure): per K-tile
//   STAGE(buf^1, next) -> ds_read(buf) -> setprio + 64 MFMA -> __syncthreads()
// Double-buffered 128 KiB LDS ([2][A 256x64 | B 256x64] bf16). The vmcnt(0)
// drain sits inside __syncthreads AFTER the MFMAs (compute covers it) — this
// is the structure the compiler schedules well; round-2/4's 3-ring counted-
// vmcnt variant measured 375 TF vs this template's 655 TF (m248, same shape).
// LDS swizzle: row chunk (16B units, 8/row) XOR'd with (row&7); staged via
// pre-swizzled GLOBAL source (src chunk = (l&7)^(l>>3), constant per lane),
// read at chunk (kk*4+quad)^(l16&7) -> conflict-free. setprio around MFMAs.
//
// G==1: A = Xb rows gathered via list, B = W1T[e] (F x D), epilogue
//       gelu(acc+b1) -> H (bf16).
// G==2: A = H rows (be+p), B = W2T[e] (D x F), split-K slab s of kslabs,
//       epilogue acc (+b2 on slab 0) -> Y[s] (f32).
// ---------------------------------------------------------------------------
template<int G>
__global__ __launch_bounds__(512, 2) void mg8_kernel(
    const bf16_t* __restrict__ Amat, const bf16_t* __restrict__ Bmat,
    const float* __restrict__ bias,
    const int* __restrict__ cnt, const int* __restrict__ base,
    const int* __restrict__ list,
    bf16_t* __restrict__ Hout, float* __restrict__ Yout)
{
    __shared__ __align__(16) bf16_t sm[2 * 32768];   // 128 KiB

    const int e  = (G == 1) ? blockIdx.z : (blockIdx.z % E_);
    const int ce = cnt[e];
    const int m0 = blockIdx.y * 256;
    if (m0 >= ce) return;
    const int n0 = blockIdx.x * 256;
    const int be = base[e];

    const int Kfull = (G == 1) ? D_ : F_;
    int klen, kbase, slab;
    if (G == 1) { klen = D_; kbase = 0; slab = 0; }
    else {
        const int kslabs = gridDim.z / E_;
        slab  = blockIdx.z / E_;
        klen  = F_ / kslabs;
        kbase = slab * klen;
    }
    const int nkt = klen / 64;

    const int tid  = threadIdx.x;
    const int lane = tid & 63, wave = tid >> 6;
    const int l16 = lane & 15, quad = lane >> 4;
    const int wm = wave >> 2, wn = wave & 3;

    // ---- staging: per gld16 a wave covers 8 rows x 64 cols; lane l writes
    // (row +l/8, chunk l%8); global source chunk pre-swizzled: (l%8)^(l/8).
    const int srowl = lane >> 3;                    // 0..7
    const int sgc   = ((lane & 7) ^ srowl) * 8;     // elem offset in row

    const bf16_t* gA[4];
    const bf16_t* gB[4];
    const bf16_t* Be = Bmat + (size_t)e * F_ * D_;  // same panel size both ways
#pragma unroll
    for (int i = 0; i < 4; ++i) {
        int ra = m0 + wave * 32 + i * 8 + srowl;
        if (ra >= ce) ra = ce - 1;
        if (G == 1) gA[i] = Amat + (size_t)list[e * NTOK + ra] * D_ + sgc;
        else        gA[i] = Amat + (size_t)(be + ra) * F_ + kbase + sgc;
        const int rb = n0 + wave * 32 + i * 8 + srowl;
        gB[i] = Be + (size_t)rb * Kfull + kbase + sgc;
    }

#define STG(bb, koff) do { \
        bf16_t* la = sm + (bb) * 32768 + wave * 2048; \
        bf16_t* lb = la + 16384; \
        gld16(gA[0] + (koff), la); \
        gld16(gA[1] + (koff), la + 512); \
        gld16(gA[2] + (koff), la + 1024); \
        gld16(gA[3] + (koff), la + 1536); \
        gld16(gB[0] + (koff), lb); \
        gld16(gB[1] + (koff), lb + 512); \
        gld16(gB[2] + (koff), lb + 1024); \
        gld16(gB[3] + (koff), lb + 1536); } while (0)

    // ---- fragment read offsets (elems); swizzle folded in ----
    const int swzk[2] = { (quad ^ (l16 & 7)) * 8, ((4 + quad) ^ (l16 & 7)) * 8 };
    const int arow = (wm * 128 + l16) * 64;
    const int brow = 16384 + (wn * 64 + l16) * 64;

    f32x4 acc[8][4] = {};

    STG(0, 0);
    __syncthreads();

    int buf = 0;
    for (int kt = 0; kt < nkt; ++kt) {
        if (kt + 1 < nkt) STG(buf ^ 1, (kt + 1) * 64);
        const bf16_t* bp = sm + buf * 32768;
#pragma unroll
        for (int kk = 0; kk < 2; ++kk) {
            i32x4 af[8], bv[4];
#pragma unroll
            for (int m = 0; m < 8; ++m)
                af[m] = *(const i32x4*)(bp + arow + m * 1024 + swzk[kk]);
#pragma unroll
            for (int n = 0; n < 4; ++n)
                bv[n] = *(const i32x4*)(bp + brow + n * 1024 + swzk[kk]);
            __builtin_amdgcn_s_setprio(1);
#pragma unroll
            for (int m = 0; m < 8; ++m)
#pragma unroll
                for (int n = 0; n < 4; ++n)
                    mfma16(af[m], bv[n], acc[m][n]);
            __builtin_amdgcn_s_setprio(0);
        }
        __syncthreads();
        buf ^= 1;
    }
#undef STG

    if (G == 1) {
        const float* b1e = bias + (size_t)e * F_;
#pragma unroll
        for (int n = 0; n < 4; ++n) {
            const int col = n0 + wn * 64 + n * 16 + l16;
            const float bb = b1e[col];
#pragma unroll
            for (int m = 0; m < 8; ++m) {
                const int pr = m0 + wm * 128 + m * 16 + quad * 4;
#pragma unroll
                for (int r = 0; r < 4; ++r) {
                    const int p = pr + r;
                    if (p < ce)
                        Hout[(size_t)(be + p) * F_ + col] =
                            f2bf_rne(gelu_exact(acc[m][n][r] + bb));
                }
            }
        }
    } else {
        float* Ys = Yout + (size_t)slab * NROW * D_;
        const float* b2e = bias + (size_t)e * D_;
#pragma unroll
        for (int n = 0; n < 4; ++n) {
            const int col = n0 + wn * 64 + n * 16 + l16;
            const float bb = (slab == 0) ? b2e[col] : 0.f;
#pragma unroll
            for (int m = 0; m < 8; ++m) {
                const int pr = m0 + wm * 128 + m * 16 + quad * 4;
#pragma unroll
                for (int r = 0; r < 4; ++r) {
                    const int p = pr + r;
                    if (p < ce)
                        Ys[(size_t)(be + p) * D_ + col] = acc[m][n][r] + bb;
                }
            }
        }
    }
}

// ---------------------------------------------------------------------------
// Combine: out[n] = sum_k w_k * (sum_s Y_s[row_k])
// ---------------------------------------------------------------------------
__global__ __launch_bounds__(256) void combine_kernel(
    const float* __restrict__ Y, const int* __restrict__ slot,
    const float* __restrict__ tw, const int* __restrict__ base,
    float* __restrict__ out, int kslabs)
{
    const int n = blockIdx.x;
    const int t = threadIdx.x;
    const int s0 = slot[n * TOPK + 0], s1 = slot[n * TOPK + 1];
    const float w0 = tw[n * TOPK + 0], w1 = tw[n * TOPK + 1];
    const int r0 = base[s0 >> 16] + (s0 & 0xffff);
    const int r1 = base[s1 >> 16] + (s1 & 0xffff);
    float4 y0 = ((const float4*)(Y + (size_t)r0 * D_))[t];
    float4 y1 = ((const float4*)(Y + (size_t)r1 * D_))[t];
    if (kslabs == 2) {
        const float* Y1 = Y + (size_t)NROW * D_;
        const float4 a = ((const float4*)(Y1 + (size_t)r0 * D_))[t];
        const float4 b = ((const float4*)(Y1 + (size_t)r1 * D_))[t];
        y0.x += a.x; y0.y += a.y; y0.z += a.z; y0.w += a.w;
        y1.x += b.x; y1.y += b.y; y1.z += b.z; y1.w += b.w;
    }
    float4 o;
    o.x = w0 * y0.x + w1 * y1.x;
    o.y = w0 * y0.y + w1 * y1.y;
    o.z = w0 * y0.z + w1 * y1.z;
    o.w = w0 * y0.w + w1 * y1.w;
    ((float4*)(out + (size_t)n * D_))[t] = o;
}

// ===========================================================================
// Fallback paths (round-2 proven kernels)
// ===========================================================================
#define BM 128
#define BN 128
#define BK 16

__global__ __launch_bounds__(256) void gemm1_kernel(
    const float* __restrict__ x, const float* __restrict__ W1,
    const float* __restrict__ b1,
    const int* __restrict__ cnt, const int* __restrict__ base,
    const int* __restrict__ list, bf16_t* __restrict__ H)
{
    __shared__ __align__(16) float Xs[BK][BM + 4];
    __shared__ __align__(16) float Ws[BK][BN + 4];

    const int e  = blockIdx.z;
    const int ce = cnt[e];
    const int m0 = blockIdx.y * BM;
    if (m0 >= ce) return;
    const int n0 = blockIdx.x * BN;
    const int be = base[e];
    const int t  = threadIdx.x;
    const int tx = t & 15, ty = t >> 4;

    const int xr_row = t >> 1;
    const int xr_c0  = (t & 1) * 8;
    const int p_x    = m0 + xr_row;
    const float* xrow = (p_x < ce) ? (x + (size_t)list[e * NTOK + p_x] * D_) : nullptr;
    const int wr_kk = t >> 4;
    const int wr_c0 = (t & 15) * 8;
    const float* W1e = W1 + (size_t)e * D_ * F_;

    float acc[8][8];
#pragma unroll
    for (int i = 0; i < 8; ++i)
#pragma unroll
        for (int j = 0; j < 8; ++j) acc[i][j] = 0.f;

    for (int k0 = 0; k0 < D_; k0 += BK) {
        float xv[8];
        if (xrow) {
            const float4 a = *(const float4*)(xrow + k0 + xr_c0);
            const float4 b = *(const float4*)(xrow + k0 + xr_c0 + 4);
            xv[0]=a.x; xv[1]=a.y; xv[2]=a.z; xv[3]=a.w;
            xv[4]=b.x; xv[5]=b.y; xv[6]=b.z; xv[7]=b.w;
        } else {
#pragma unroll
            for (int j = 0; j < 8; ++j) xv[j] = 0.f;
        }
#pragma unroll
        for (int j = 0; j < 8; ++j) Xs[xr_c0 + j][xr_row] = xv[j];
        {
            const float* wr = W1e + (size_t)(k0 + wr_kk) * F_ + (n0 + wr_c0);
            *(float4*)&Ws[wr_kk][wr_c0]     = *(const float4*)(wr);
            *(float4*)&Ws[wr_kk][wr_c0 + 4] = *(const float4*)(wr + 4);
        }
        __syncthreads();
#pragma unroll 4
        for (int kk = 0; kk < BK; ++kk) {
            float a[8], b[8];
            *(float4*)&a[0] = *(const float4*)&Xs[kk][ty * 8];
            *(float4*)&a[4] = *(const float4*)&Xs[kk][ty * 8 + 4];
            *(float4*)&b[0] = *(const float4*)&Ws[kk][tx * 8];
            *(float4*)&b[4] = *(const float4*)&Ws[kk][tx * 8 + 4];
#pragma unroll
            for (int i = 0; i < 8; ++i)
#pragma unroll
                for (int j = 0; j < 8; ++j)
                    acc[i][j] += a[i] * b[j];
        }
        __syncthreads();
    }

    const float* b1e = b1 + (size_t)e * F_;
    float bb[8];
#pragma unroll
    for (int j = 0; j < 8; ++j) bb[j] = b1e[n0 + tx * 8 + j];
#pragma unroll
    for (int i = 0; i < 8; ++i) {
        const int p = m0 + ty * 8 + i;
        if (p >= ce) continue;
        unsigned int pk[4];
#pragma unroll
        for (int jj = 0; jj < 4; ++jj) {
            const float g0 = gelu_exact(acc[i][2 * jj]     + bb[2 * jj]);
            const float g1 = gelu_exact(acc[i][2 * jj + 1] + bb[2 * jj + 1]);
            pk[jj] = (unsigned int)f2bf_rne(g0) | ((unsigned int)f2bf_rne(g1) << 16);
        }
        uint4 v; v.x = pk[0]; v.y = pk[1]; v.z = pk[2]; v.w = pk[3];
        *(uint4*)(H + (size_t)(be + p) * F_ + n0 + tx * 8) = v;
    }
}

__global__ __launch_bounds__(256) void gemm2_kernel(
    const bf16_t* __restrict__ H, const float* __restrict__ W2,
    const float* __restrict__ b2,
    const int* __restrict__ cnt, const int* __restrict__ base,
    const int* __restrict__ list, const float* __restrict__ wgt,
    float* __restrict__ out)
{
    __shared__ __align__(16) float Hs[BK][BM + 4];
    __shared__ __align__(16) float Ws[BK][BN + 4];

    const int e  = blockIdx.z;
    const int ce = cnt[e];
    const int m0 = blockIdx.y * BM;
    if (m0 >= ce) return;
    const int n0 = blockIdx.x * BN;
    const int be = base[e];
    const int t  = threadIdx.x;
    const int tx = t & 15, ty = t >> 4;

    const int hr_row = t >> 1;
    const int hr_c0  = (t & 1) * 8;
    const int p_h    = m0 + hr_row;
    const bf16_t* hrow = (p_h < ce) ? (H + (size_t)(be + p_h) * F_) : nullptr;
    const int wr_kk = t >> 4;
    const int wr_c0 = (t & 15) * 8;
    const float* W2e = W2 + (size_t)e * F_ * D_;

    float acc[8][8];
#pragma unroll
    for (int i = 0; i < 8; ++i)
#pragma unroll
        for (int j = 0; j < 8; ++j) acc[i][j] = 0.f;

    for (int k0 = 0; k0 < F_; k0 += BK) {
        float hv[8];
        if (hrow) {
            const uint4 u = *(const uint4*)(hrow + k0 + hr_c0);
            hv[0] = bf2f(u.x & 0xffffu); hv[1] = bf2f(u.x >> 16);
            hv[2] = bf2f(u.y & 0xffffu); hv[3] = bf2f(u.y >> 16);
            hv[4] = bf2f(u.z & 0xffffu); hv[5] = bf2f(u.z >> 16);
            hv[6] = bf2f(u.w & 0xffffu); hv[7] = bf2f(u.w >> 16);
        } else {
#pragma unroll
            for (int j = 0; j < 8; ++j) hv[j] = 0.f;
        }
#pragma unroll
        for (int j = 0; j < 8; ++j) Hs[hr_c0 + j][hr_row] = hv[j];
        {
            const float* wr = W2e + (size_t)(k0 + wr_kk) * D_ + (n0 + wr_c0);
            *(float4*)&Ws[wr_kk][wr_c0]     = *(const float4*)(wr);
            *(float4*)&Ws[wr_kk][wr_c0 + 4] = *(const float4*)(wr + 4);
        }
        __syncthreads();
#pragma unroll 4
        for (int kk = 0; kk < BK; ++kk) {
            float a[8], b[8];
            *(float4*)&a[0] = *(const float4*)&Hs[kk][ty * 8];
            *(float4*)&a[4] = *(const float4*)&Hs[kk][ty * 8 + 4];
            *(float4*)&b[0] = *(const float4*)&Ws[kk][tx * 8];
            *(float4*)&b[4] = *(const float4*)&Ws[kk][tx * 8 + 4];
#pragma unroll
            for (int i = 0; i < 8; ++i)
#pragma unroll
                for (int j = 0; j < 8; ++j)
                    acc[i][j] += a[i] * b[j];
        }
        __syncthreads();
    }

    const float* b2e = b2 + (size_t)e * D_;
    float bb[8];
#pragma unroll
    for (int j = 0; j < 8; ++j) bb[j] = b2e[n0 + tx * 8 + j];
#pragma unroll
    for (int i = 0; i < 8; ++i) {
        const int p = m0 + ty * 8 + i;
        if (p >= ce) continue;
        const int   n = list[e * NTOK + p];
        const float w = wgt[e * NTOK + p];
        float* op = out + (size_t)n * D_ + n0 + tx * 8;
#pragma unroll
        for (int j = 0; j < 8; ++j)
            atomicAdd(&op[j], w * (acc[i][j] + bb[j]));
    }
}

__global__ __launch_bounds__(256) void fallback_expert_kernel(
    const float* __restrict__ x,
    const float* __restrict__ W1, const float* __restrict__ b1,
    const float* __restrict__ W2, const float* __restrict__ b2,
    const int* __restrict__ top_idx, const float* __restrict__ top_w,
    float* __restrict__ out)
{
    __shared__ float x_lds[D_];
    __shared__ float h_lds[F_];

    const int n = blockIdx.x;
    const int t = threadIdx.x;

    ((float4*)x_lds)[t] = ((const float4*)(x + (size_t)n * D_))[t];
    __syncthreads();

    const int d0 = t * 4;
    float acc_out[4] = {0.f, 0.f, 0.f, 0.f};

    for (int k = 0; k < TOPK; ++k) {
        const int   e = top_idx[n * TOPK + k];
        const float w = top_w[n * TOPK + k];
        const float* W1e = W1 + (size_t)e * D_ * F_;
        const float* b1e = b1 + (size_t)e * F_;
#pragma unroll
        for (int tile = 0; tile < 2; ++tile) {
            const int base_f = tile * 2048 + t * 8;
            float a[8];
#pragma unroll
            for (int j = 0; j < 8; ++j) a[j] = b1e[base_f + j];
            const float4* wp = (const float4*)(W1e + base_f);
            for (int d = 0; d < D_; ++d) {
                const float4 w0 = wp[(size_t)d * (F_ / 4)];
                const float4 w1 = wp[(size_t)d * (F_ / 4) + 1];
                const float xv = x_lds[d];
                a[0] += xv * w0.x; a[1] += xv * w0.y;
                a[2] += xv * w0.z; a[3] += xv * w0.w;
                a[4] += xv * w1.x; a[5] += xv * w1.y;
                a[6] += xv * w1.z; a[7] += xv * w1.w;
            }
#pragma unroll
            for (int j = 0; j < 8; ++j)
                h_lds[base_f + j] = gelu_exact(a[j]);
        }
        __syncthreads();

        const float* W2e = W2 + (size_t)e * F_ * D_;
        const float* b2e = b2 + (size_t)e * D_;
        float y[4];
#pragma unroll
        for (int j = 0; j < 4; ++j) y[j] = b2e[d0 + j];
        const float4* wp2 = (const float4*)(W2e + d0);
        for (int f = 0; f < F_; ++f) {
            const float4 wv = wp2[(size_t)f * (D_ / 4)];
            const float hv = h_lds[f];
            y[0] += hv * wv.x; y[1] += hv * wv.y;
            y[2] += hv * wv.z; y[3] += hv * wv.w;
        }
#pragma unroll
        for (int j = 0; j < 4; ++j) acc_out[j] += w * y[j];
        __syncthreads();
    }

    float4 o; o.x = acc_out[0]; o.y = acc_out[1]; o.z = acc_out[2]; o.w = acc_out[3];
    *(float4*)(out + (size_t)n * D_ + d0) = o;
}

extern "C" void kernel_launch(void* const* d_in, const int* in_sizes, int n_in,
                              void* d_out, int out_size, void* d_ws, size_t ws_size,
                              hipStream_t stream) {
    const float* x  = (const float*)d_in[0];
    const float* Wr = (const float*)d_in[1];
    const float* W1 = (const float*)d_in[2];
    const float* b1 = (const float*)d_in[3];
    const float* W2 = (const float*)d_in[4];
    const float* b2 = (const float*)d_in[5];
    float* out = (float*)d_out;

    char* ws = (char*)d_ws;
    int*    cnt   = (int*)(ws + OFF_CNT);
    int*    basep = (int*)(ws + OFF_BASE);
    int*    tidx  = (int*)(ws + OFF_TIDX);
    float*  tw    = (float*)(ws + OFF_TW);
    int*    list  = (int*)(ws + OFF_LIST);
    float*  wgt   = (float*)(ws + OFF_WGT);

    if (ws_size >= WS_MFMA) {
        const int kslabs = (ws_size >= WS_MFMA2) ? 2 : 1;
        int*    slot = (int*)(ws + OFF_SLOT);
        bf16_t* Xb   = (bf16_t*)(ws + OFF_XB);
        bf16_t* W1T  = (bf16_t*)(ws + OFF_W1T);
        bf16_t* W2T  = (bf16_t*)(ws + OFF_W2T);
        bf16_t* H    = (bf16_t*)(ws + OFF_HN);
        float*  Y    = (float*)(ws + OFF_Y);

        hipMemsetAsync(cnt, 0, E_ * sizeof(int), stream);
        router_kernel<<<NTOK, 64, 0, stream>>>(x, Wr, tidx, tw, cnt, list, wgt, slot, 3);
        prefix_kernel<<<1, 64, 0, stream>>>(cnt, basep);
        convert_x_kernel<<<NTOK * D_ / 4 / 256, 256, 0, stream>>>(x, Xb);
        transpose_kernel<<<dim3(F_ / 64, D_ / 64, E_), 256, 0, stream>>>(W1, W1T, D_, F_);
        transpose_kernel<<<dim3(D_ / 64, F_ / 64, E_), 256, 0, stream>>>(W2, W2T, F_, D_);
        mg8_kernel<1><<<dim3(F_ / 256, NTOK / 256, E_), 512, 0, stream>>>(
            Xb, W1T, b1, cnt, basep, list, H, nullptr);
        mg8_kernel<2><<<dim3(D_ / 256, NTOK / 256, E_ * kslabs), 512, 0, stream>>>(
            H, W2T, b2, cnt, basep, nullptr, nullptr, Y);
        combine_kernel<<<NTOK, 256, 0, stream>>>(Y, slot, tw, basep, out, kslabs);
    } else if (ws_size >= WS_OLD) {
        bf16_t* H = (bf16_t*)(ws + OFF_H_OLD);
        hipMemsetAsync(cnt, 0, E_ * sizeof(int), stream);
        router_kernel<<<NTOK, 64, 0, stream>>>(x, Wr, tidx, tw, cnt, list, wgt, nullptr, 1);
        prefix_kernel<<<1, 64, 0, stream>>>(cnt, basep);
        hipMemsetAsync(out, 0, (size_t)NTOK * D_ * sizeof(float), stream);
        gemm1_kernel<<<dim3(F_ / BN, NTOK / BM, E_), 256, 0, stream>>>(
            x, W1, b1, cnt, basep, list, H);
        gemm2_kernel<<<dim3(D_ / BN, NTOK / BM, E_), 256, 0, stream>>>(
            H, W2, b2, cnt, basep, list, wgt, out);
    } else {
        router_kernel<<<NTOK, 64, 0, stream>>>(x, Wr, tidx, tw, cnt, list, wgt, nullptr, 0);
        fallback_expert_kernel<<<NTOK, 256, 0, stream>>>(
            x, W1, b1, W2, b2, tidx, tw, out);
    }
}

// Round 6
// 720.898 us; speedup vs baseline: 1.0219x; 1.0136x over previous
//
#include <hip/hip_runtime.h>
#include <hip/hip_bf16.h>
#include <math.h>

#define B_  2
#define T_  2048
#define D_  1024
#define F_  4096
#define E_  8
#define NTOK 4096       // B_*T_
#define TOPK 2
#define NROW 8192       // NTOK*TOPK total selected rows

typedef unsigned short bf16_t;
typedef float f32x4 __attribute__((ext_vector_type(4)));
typedef int   i32x4 __attribute__((ext_vector_type(4)));
typedef __bf16 bf16x8 __attribute__((ext_vector_type(8)));

// ---- ws layout (bytes) ----
#define OFF_CNT   0                          // int[8]
#define OFF_BASE  32                         // int[8]
#define OFF_TIDX  64                         // int[NTOK*2]
#define OFF_TW    32832                      // float[NTOK*2]
#define OFF_LIST  65600                      // int[8*4096]
#define OFF_WGT   196672                     // float[8*4096]
// old (round-2) path
#define OFF_H_OLD 327744                     // bf16[8192*4096] = 64 MB
#define WS_OLD    (OFF_H_OLD + (size_t)NROW * F_ * 2)
// MFMA path
#define OFF_SLOT  327744                     // int[NTOK*2]  (e<<16 | pos)
#define OFF_XB    (1u << 20)                 // bf16[NTOK*D]      8 MB
#define OFF_W1T   (OFF_XB  + (size_t)NTOK * D_ * 2)         // bf16[E*F*D] 64 MB
#define OFF_W2T   (OFF_W1T + (size_t)E_ * F_ * D_ * 2)      // bf16[E*D*F] 64 MB
#define OFF_HN    (OFF_W2T + (size_t)E_ * D_ * F_ * 2)      // bf16[NROW*F] 64 MB
#define OFF_Y     (OFF_HN  + (size_t)NROW * F_ * 2)         // f32[NROW*D] per slab
#define WS_MFMA   (OFF_Y + (size_t)NROW * D_ * 4)           // 1 slab
#define WS_MFMA2  (OFF_Y + 2 * (size_t)NROW * D_ * 4)       // 2 slabs

__device__ __forceinline__ float gelu_exact(float v) {
    return 0.5f * v * (1.0f + erff(v * 0.70710678118654752440f));
}

__device__ __forceinline__ unsigned short f2bf_rne(float f) {
    union { float f; unsigned int u; } v; v.f = f;
    unsigned int r = (v.u + 0x7fffu + ((v.u >> 16) & 1u)) >> 16;
    return (unsigned short)r;
}

__device__ __forceinline__ float bf2f(unsigned int u) {
    union { unsigned int i; float f; } v; v.i = u << 16; return v.f;
}

// async 16B/lane global->LDS; lds base wave-uniform (+lane*16 implicit)
__device__ __forceinline__ void gld16(const void* g, void* l) {
    __builtin_amdgcn_global_load_lds(
        (const __attribute__((address_space(1))) unsigned int*)g,
        (__attribute__((address_space(3))) unsigned int*)l, 16, 0, 0);
}

__device__ __forceinline__ void mfma16(const i32x4& a, const i32x4& b, f32x4& c) {
    c = __builtin_amdgcn_mfma_f32_16x16x32_bf16(
        __builtin_bit_cast(bf16x8, a), __builtin_bit_cast(bf16x8, b), c, 0, 0, 0);
}

// ---------------------------------------------------------------------------
// Router
// ---------------------------------------------------------------------------
__global__ __launch_bounds__(64) void router_kernel(
    const float* __restrict__ x, const float* __restrict__ Wr,
    int* __restrict__ top_idx, float* __restrict__ top_w,
    int* __restrict__ cnt, int* __restrict__ list, float* __restrict__ wgt,
    int* __restrict__ slot, int mode)
{
    const int n = blockIdx.x;
    const int lane = threadIdx.x;
    const float* xr = x + (size_t)n * D_;

    float acc[E_];
#pragma unroll
    for (int e = 0; e < E_; ++e) acc[e] = 0.f;

    for (int d = lane; d < D_; d += 64) {
        const float xv = xr[d];
#pragma unroll
        for (int e = 0; e < E_; ++e)
            acc[e] += xv * Wr[d * E_ + e];
    }
#pragma unroll
    for (int e = 0; e < E_; ++e) {
        float v = acc[e];
#pragma unroll
        for (int off = 32; off > 0; off >>= 1)
            v += __shfl_down(v, off, 64);
        acc[e] = v;
    }
    if (lane == 0) {
        float m = acc[0];
#pragma unroll
        for (int e = 1; e < E_; ++e) m = fmaxf(m, acc[e]);
        float p[E_];
#pragma unroll
        for (int e = 0; e < E_; ++e) p[e] = __expf(acc[e] - m);
        int i0 = 0; float v0 = p[0];
#pragma unroll
        for (int e = 1; e < E_; ++e) if (p[e] > v0) { v0 = p[e]; i0 = e; }
        int i1 = (i0 == 0) ? 1 : 0; float v1 = p[i1];
#pragma unroll
        for (int e = 0; e < E_; ++e) {
            if (e == i0) continue;
            if (p[e] > v1) { v1 = p[e]; i1 = e; }
        }
        const float inv = 1.f / (v0 + v1);
        const float w0 = v0 * inv, w1 = v1 * inv;
        top_idx[n * TOPK + 0] = i0;
        top_idx[n * TOPK + 1] = i1;
        top_w[n * TOPK + 0] = w0;
        top_w[n * TOPK + 1] = w1;
        if (mode & 1) {
            int p0 = atomicAdd(&cnt[i0], 1);
            list[i0 * NTOK + p0] = n;  wgt[i0 * NTOK + p0] = w0;
            int p1 = atomicAdd(&cnt[i1], 1);
            list[i1 * NTOK + p1] = n;  wgt[i1 * NTOK + p1] = w1;
            if (mode & 2) {
                slot[n * TOPK + 0] = (i0 << 16) | p0;
                slot[n * TOPK + 1] = (i1 << 16) | p1;
            }
        }
    }
}

__global__ void prefix_kernel(const int* __restrict__ cnt, int* __restrict__ base)
{
    if (threadIdx.x == 0 && blockIdx.x == 0) {
        int s = 0;
#pragma unroll
        for (int e = 0; e < E_; ++e) { base[e] = s; s += cnt[e]; }
    }
}

// ---------------------------------------------------------------------------
// f32 -> bf16 cast of x
// ---------------------------------------------------------------------------
__global__ __launch_bounds__(256) void convert_x_kernel(
    const float* __restrict__ x, bf16_t* __restrict__ xb)
{
    const int i = blockIdx.x * 256 + threadIdx.x;
    const float4 v = ((const float4*)x)[i];
    uint2 o;
    o.x = (unsigned int)f2bf_rne(v.x) | ((unsigned int)f2bf_rne(v.y) << 16);
    o.y = (unsigned int)f2bf_rne(v.z) | ((unsigned int)f2bf_rne(v.w) << 16);
    ((uint2*)xb)[i] = o;
}

// ---------------------------------------------------------------------------
// Batched transpose: src f32 [Z][R][C] -> dst bf16 [Z][C][R], 64x64 tiles.
// ---------------------------------------------------------------------------
__global__ __launch_bounds__(256) void transpose_kernel(
    const float* __restrict__ src, bf16_t* __restrict__ dst, int R, int C)
{
    __shared__ float tile[64][65];
    const int z  = blockIdx.z;
    const int r0 = blockIdx.y * 64;
    const int c0 = blockIdx.x * 64;
    const float* s = src + (size_t)z * R * C;
    bf16_t*      d = dst + (size_t)z * R * C;
#pragma unroll
    for (int i = 0; i < 4; ++i) {
        const int r  = i * 16 + (threadIdx.x >> 4);
        const int c4 = (threadIdx.x & 15) * 4;
        const float4 v = *(const float4*)(s + (size_t)(r0 + r) * C + c0 + c4);
        tile[r][c4]     = v.x;
        tile[r][c4 + 1] = v.y;
        tile[r][c4 + 2] = v.z;
        tile[r][c4 + 3] = v.w;
    }
    __syncthreads();
    const int rc = (threadIdx.x & 15) * 4;
    const int cc = threadIdx.x >> 4;   // 0..15
#pragma unroll
    for (int i = 0; i < 4; ++i) {
        const int c = i * 16 + cc;
        uint2 o;
        o.x = (unsigned int)f2bf_rne(tile[rc    ][c]) | ((unsigned int)f2bf_rne(tile[rc + 1][c]) << 16);
        o.y = (unsigned int)f2bf_rne(tile[rc + 2][c]) | ((unsigned int)f2bf_rne(tile[rc + 3][c]) << 16);
        *(uint2*)(d + (size_t)(c0 + c) * R + r0 + rc) = o;
    }
}

// ---------------------------------------------------------------------------
// Grouped MFMA GEMM, 256x256 tile, BK=64, 512 threads (8 waves, 2Mx4N).
// 2-phase template (unchanged from round 5). ROUND 6 CHANGE: 1-D grid with a
// CONTIGUOUS-WORKING-PREFIX decode. The old 3-D grid put working blocks
// (mt < ce/256, i.e. the low quarter of each expert stripe) at linear ids
// z*256 + [0..63] -- ids = 0..63 (mod 256) for EVERY stripe, aliasing all 512
// working blocks onto the same quarter of the CUs under modular dispatch
// (loaded CUs measured at ~73% of per-CU MFMA ceiling x 25% CUs = the
// invariant 17% MfmaUtil across rounds 2/4/5). New decode puts the sparse
// M-tile dim SLOWEST:  id = mt*(E*NSLAB*NX) + e*(NSLAB*NX) + slab*NX + xt,
// so working blocks are ids [0 .. ~512) -- a contiguous prefix that spreads
// evenly over all 256 CUs; xt fastest keeps A-panel L2 reuse.
//
// G==1: A = Xb rows gathered via list, B = W1T[e] (F x D), epilogue
//       gelu(acc+b1) -> H (bf16).   grid = 16mt*8e*16xt = 2048 blocks.
// G==2: A = H rows (be+p), B = W2T[e] (D x F), split-K slab of kslabs,
//       epilogue acc (+b2 slab 0) -> Y[s] (f32). grid = 512*kslabs.
// ---------------------------------------------------------------------------
template<int G>
__global__ __launch_bounds__(512, 2) void mg8_kernel(
    const bf16_t* __restrict__ Amat, const bf16_t* __restrict__ Bmat,
    const float* __restrict__ bias,
    const int* __restrict__ cnt, const int* __restrict__ base,
    const int* __restrict__ list,
    bf16_t* __restrict__ Hout, float* __restrict__ Yout)
{
    __shared__ __align__(16) bf16_t sm[2 * 32768];   // 128 KiB

    // ---- contiguous-working-prefix decode (mt slowest, xt fastest) ----
    const int NX = (G == 1) ? (F_ / 256) : (D_ / 256);
    int e, mt, xt, slab, klen, kbase;
    {
        const int bid = blockIdx.x;
        xt = bid % NX;
        int rem = bid / NX;
        if (G == 1) {
            slab = 0; klen = D_; kbase = 0;
        } else {
            const int kslabs = gridDim.x / (NX * E_ * (NTOK / 256));
            slab = rem % kslabs; rem /= kslabs;
            klen = F_ / kslabs; kbase = slab * klen;
        }
        e  = rem % E_;
        mt = rem / E_;
    }
    const int ce = cnt[e];
    const int m0 = mt * 256;
    if (m0 >= ce) return;
    const int n0 = xt * 256;
    const int be = base[e];
    const int Kfull = (G == 1) ? D_ : F_;
    const int nkt = klen / 64;

    const int tid  = threadIdx.x;
    const int lane = tid & 63, wave = tid >> 6;
    const int l16 = lane & 15, quad = lane >> 4;
    const int wm = wave >> 2, wn = wave & 3;

    // ---- staging: per gld16 a wave covers 8 rows x 64 cols; lane l writes
    // (row +l/8, chunk l%8); global source chunk pre-swizzled: (l%8)^(l/8).
    const int srowl = lane >> 3;                    // 0..7
    const int sgc   = ((lane & 7) ^ srowl) * 8;     // elem offset in row

    const bf16_t* gA[4];
    const bf16_t* gB[4];
    const bf16_t* Be = Bmat + (size_t)e * F_ * D_;  // same panel size both ways
#pragma unroll
    for (int i = 0; i < 4; ++i) {
        int ra = m0 + wave * 32 + i * 8 + srowl;
        if (ra >= ce) ra = ce - 1;
        if (G == 1) gA[i] = Amat + (size_t)list[e * NTOK + ra] * D_ + sgc;
        else        gA[i] = Amat + (size_t)(be + ra) * F_ + kbase + sgc;
        const int rb = n0 + wave * 32 + i * 8 + srowl;
        gB[i] = Be + (size_t)rb * Kfull + kbase + sgc;
    }

#define STG(bb, koff) do { \
        bf16_t* la = sm + (bb) * 32768 + wave * 2048; \
        bf16_t* lb = la + 16384; \
        gld16(gA[0] + (koff), la); \
        gld16(gA[1] + (koff), la + 512); \
        gld16(gA[2] + (koff), la + 1024); \
        gld16(gA[3] + (koff), la + 1536); \
        gld16(gB[0] + (koff), lb); \
        gld16(gB[1] + (koff), lb + 512); \
        gld16(gB[2] + (koff), lb + 1024); \
        gld16(gB[3] + (koff), lb + 1536); } while (0)

    // ---- fragment read offsets (elems); swizzle folded in ----
    const int swzk[2] = { (quad ^ (l16 & 7)) * 8, ((4 + quad) ^ (l16 & 7)) * 8 };
    const int arow = (wm * 128 + l16) * 64;
    const int brow = 16384 + (wn * 64 + l16) * 64;

    f32x4 acc[8][4] = {};

    STG(0, 0);
    __syncthreads();

    int buf = 0;
    for (int kt = 0; kt < nkt; ++kt) {
        if (kt + 1 < nkt) STG(buf ^ 1, (kt + 1) * 64);
        const bf16_t* bp = sm + buf * 32768;
#pragma unroll
        for (int kk = 0; kk < 2; ++kk) {
            i32x4 af[8], bv[4];
#pragma unroll
            for (int m = 0; m < 8; ++m)
                af[m] = *(const i32x4*)(bp + arow + m * 1024 + swzk[kk]);
#pragma unroll
            for (int n = 0; n < 4; ++n)
                bv[n] = *(const i32x4*)(bp + brow + n * 1024 + swzk[kk]);
            __builtin_amdgcn_s_setprio(1);
#pragma unroll
            for (int m = 0; m < 8; ++m)
#pragma unroll
                for (int n = 0; n < 4; ++n)
                    mfma16(af[m], bv[n], acc[m][n]);
            __builtin_amdgcn_s_setprio(0);
        }
        __syncthreads();
        buf ^= 1;
    }
#undef STG

    if (G == 1) {
        const float* b1e = bias + (size_t)e * F_;
#pragma unroll
        for (int n = 0; n < 4; ++n) {
            const int col = n0 + wn * 64 + n * 16 + l16;
            const float bb = b1e[col];
#pragma unroll
            for (int m = 0; m < 8; ++m) {
                const int pr = m0 + wm * 128 + m * 16 + quad * 4;
#pragma unroll
                for (int r = 0; r < 4; ++r) {
                    const int p = pr + r;
                    if (p < ce)
                        Hout[(size_t)(be + p) * F_ + col] =
                            f2bf_rne(gelu_exact(acc[m][n][r] + bb));
                }
            }
        }
    } else {
        float* Ys = Yout + (size_t)slab * NROW * D_;
        const float* b2e = bias + (size_t)e * D_;
#pragma unroll
        for (int n = 0; n < 4; ++n) {
            const int col = n0 + wn * 64 + n * 16 + l16;
            const float bb = (slab == 0) ? b2e[col] : 0.f;
#pragma unroll
            for (int m = 0; m < 8; ++m) {
                const int pr = m0 + wm * 128 + m * 16 + quad * 4;
#pragma unroll
                for (int r = 0; r < 4; ++r) {
                    const int p = pr + r;
                    if (p < ce)
                        Ys[(size_t)(be + p) * D_ + col] = acc[m][n][r] + bb;
                }
            }
        }
    }
}

// ---------------------------------------------------------------------------
// Combine: out[n] = sum_k w_k * (sum_s Y_s[row_k])
// ---------------------------------------------------------------------------
__global__ __launch_bounds__(256) void combine_kernel(
    const float* __restrict__ Y, const int* __restrict__ slot,
    const float* __restrict__ tw, const int* __restrict__ base,
    float* __restrict__ out, int kslabs)
{
    const int n = blockIdx.x;
    const int t = threadIdx.x;
    const int s0 = slot[n * TOPK + 0], s1 = slot[n * TOPK + 1];
    const float w0 = tw[n * TOPK + 0], w1 = tw[n * TOPK + 1];
    const int r0 = base[s0 >> 16] + (s0 & 0xffff);
    const int r1 = base[s1 >> 16] + (s1 & 0xffff);
    float4 y0 = ((const float4*)(Y + (size_t)r0 * D_))[t];
    float4 y1 = ((const float4*)(Y + (size_t)r1 * D_))[t];
    if (kslabs == 2) {
        const float* Y1 = Y + (size_t)NROW * D_;
        const float4 a = ((const float4*)(Y1 + (size_t)r0 * D_))[t];
        const float4 b = ((const float4*)(Y1 + (size_t)r1 * D_))[t];
        y0.x += a.x; y0.y += a.y; y0.z += a.z; y0.w += a.w;
        y1.x += b.x; y1.y += b.y; y1.z += b.z; y1.w += b.w;
    }
    float4 o;
    o.x = w0 * y0.x + w1 * y1.x;
    o.y = w0 * y0.y + w1 * y1.y;
    o.z = w0 * y0.z + w1 * y1.z;
    o.w = w0 * y0.w + w1 * y1.w;
    ((float4*)(out + (size_t)n * D_))[t] = o;
}

// ===========================================================================
// Fallback paths (round-2 proven kernels)
// ===========================================================================
#define BM 128
#define BN 128
#define BK 16

__global__ __launch_bounds__(256) void gemm1_kernel(
    const float* __restrict__ x, const float* __restrict__ W1,
    const float* __restrict__ b1,
    const int* __restrict__ cnt, const int* __restrict__ base,
    const int* __restrict__ list, bf16_t* __restrict__ H)
{
    __shared__ __align__(16) float Xs[BK][BM + 4];
    __shared__ __align__(16) float Ws[BK][BN + 4];

    const int e  = blockIdx.z;
    const int ce = cnt[e];
    const int m0 = blockIdx.y * BM;
    if (m0 >= ce) return;
    const int n0 = blockIdx.x * BN;
    const int be = base[e];
    const int t  = threadIdx.x;
    const int tx = t & 15, ty = t >> 4;

    const int xr_row = t >> 1;
    const int xr_c0  = (t & 1) * 8;
    const int p_x    = m0 + xr_row;
    const float* xrow = (p_x < ce) ? (x + (size_t)list[e * NTOK + p_x] * D_) : nullptr;
    const int wr_kk = t >> 4;
    const int wr_c0 = (t & 15) * 8;
    const float* W1e = W1 + (size_t)e * D_ * F_;

    float acc[8][8];
#pragma unroll
    for (int i = 0; i < 8; ++i)
#pragma unroll
        for (int j = 0; j < 8; ++j) acc[i][j] = 0.f;

    for (int k0 = 0; k0 < D_; k0 += BK) {
        float xv[8];
        if (xrow) {
            const float4 a = *(const float4*)(xrow + k0 + xr_c0);
            const float4 b = *(const float4*)(xrow + k0 + xr_c0 + 4);
            xv[0]=a.x; xv[1]=a.y; xv[2]=a.z; xv[3]=a.w;
            xv[4]=b.x; xv[5]=b.y; xv[6]=b.z; xv[7]=b.w;
        } else {
#pragma unroll
            for (int j = 0; j < 8; ++j) xv[j] = 0.f;
        }
#pragma unroll
        for (int j = 0; j < 8; ++j) Xs[xr_c0 + j][xr_row] = xv[j];
        {
            const float* wr = W1e + (size_t)(k0 + wr_kk) * F_ + (n0 + wr_c0);
            *(float4*)&Ws[wr_kk][wr_c0]     = *(const float4*)(wr);
            *(float4*)&Ws[wr_kk][wr_c0 + 4] = *(const float4*)(wr + 4);
        }
        __syncthreads();
#pragma unroll 4
        for (int kk = 0; kk < BK; ++kk) {
            float a[8], b[8];
            *(float4*)&a[0] = *(const float4*)&Xs[kk][ty * 8];
            *(float4*)&a[4] = *(const float4*)&Xs[kk][ty * 8 + 4];
            *(float4*)&b[0] = *(const float4*)&Ws[kk][tx * 8];
            *(float4*)&b[4] = *(const float4*)&Ws[kk][tx * 8 + 4];
#pragma unroll
            for (int i = 0; i < 8; ++i)
#pragma unroll
                for (int j = 0; j < 8; ++j)
                    acc[i][j] += a[i] * b[j];
        }
        __syncthreads();
    }

    const float* b1e = b1 + (size_t)e * F_;
    float bb[8];
#pragma unroll
    for (int j = 0; j < 8; ++j) bb[j] = b1e[n0 + tx * 8 + j];
#pragma unroll
    for (int i = 0; i < 8; ++i) {
        const int p = m0 + ty * 8 + i;
        if (p >= ce) continue;
        unsigned int pk[4];
#pragma unroll
        for (int jj = 0; jj < 4; ++jj) {
            const float g0 = gelu_exact(acc[i][2 * jj]     + bb[2 * jj]);
            const float g1 = gelu_exact(acc[i][2 * jj + 1] + bb[2 * jj + 1]);
            pk[jj] = (unsigned int)f2bf_rne(g0) | ((unsigned int)f2bf_rne(g1) << 16);
        }
        uint4 v; v.x = pk[0]; v.y = pk[1]; v.z = pk[2]; v.w = pk[3];
        *(uint4*)(H + (size_t)(be + p) * F_ + n0 + tx * 8) = v;
    }
}

__global__ __launch_bounds__(256) void gemm2_kernel(
    const bf16_t* __restrict__ H, const float* __restrict__ W2,
    const float* __restrict__ b2,
    const int* __restrict__ cnt, const int* __restrict__ base,
    const int* __restrict__ list, const float* __restrict__ wgt,
    float* __restrict__ out)
{
    __shared__ __align__(16) float Hs[BK][BM + 4];
    __shared__ __align__(16) float Ws[BK][BN + 4];

    const int e  = blockIdx.z;
    const int ce = cnt[e];
    const int m0 = blockIdx.y * BM;
    if (m0 >= ce) return;
    const int n0 = blockIdx.x * BN;
    const int be = base[e];
    const int t  = threadIdx.x;
    const int tx = t & 15, ty = t >> 4;

    const int hr_row = t >> 1;
    const int hr_c0  = (t & 1) * 8;
    const int p_h    = m0 + hr_row;
    const bf16_t* hrow = (p_h < ce) ? (H + (size_t)(be + p_h) * F_) : nullptr;
    const int wr_kk = t >> 4;
    const int wr_c0 = (t & 15) * 8;
    const float* W2e = W2 + (size_t)e * F_ * D_;

    float acc[8][8];
#pragma unroll
    for (int i = 0; i < 8; ++i)
#pragma unroll
        for (int j = 0; j < 8; ++j) acc[i][j] = 0.f;

    for (int k0 = 0; k0 < F_; k0 += BK) {
        float hv[8];
        if (hrow) {
            const uint4 u = *(const uint4*)(hrow + k0 + hr_c0);
            hv[0] = bf2f(u.x & 0xffffu); hv[1] = bf2f(u.x >> 16);
            hv[2] = bf2f(u.y & 0xffffu); hv[3] = bf2f(u.y >> 16);
            hv[4] = bf2f(u.z & 0xffffu); hv[5] = bf2f(u.z >> 16);
            hv[6] = bf2f(u.w & 0xffffu); hv[7] = bf2f(u.w >> 16);
        } else {
#pragma unroll
            for (int j = 0; j < 8; ++j) hv[j] = 0.f;
        }
#pragma unroll
        for (int j = 0; j < 8; ++j) Hs[hr_c0 + j][hr_row] = hv[j];
        {
            const float* wr = W2e + (size_t)(k0 + wr_kk) * D_ + (n0 + wr_c0);
            *(float4*)&Ws[wr_kk][wr_c0]     = *(const float4*)(wr);
            *(float4*)&Ws[wr_kk][wr_c0 + 4] = *(const float4*)(wr + 4);
        }
        __syncthreads();
#pragma unroll 4
        for (int kk = 0; kk < BK; ++kk) {
            float a[8], b[8];
            *(float4*)&a[0] = *(const float4*)&Hs[kk][ty * 8];
            *(float4*)&a[4] = *(const float4*)&Hs[kk][ty * 8 + 4];
            *(float4*)&b[0] = *(const float4*)&Ws[kk][tx * 8];
            *(float4*)&b[4] = *(const float4*)&Ws[kk][tx * 8 + 4];
#pragma unroll
            for (int i = 0; i < 8; ++i)
#pragma unroll
                for (int j = 0; j < 8; ++j)
                    acc[i][j] += a[i] * b[j];
        }
        __syncthreads();
    }

    const float* b2e = b2 + (size_t)e * D_;
    float bb[8];
#pragma unroll
    for (int j = 0; j < 8; ++j) bb[j] = b2e[n0 + tx * 8 + j];
#pragma unroll
    for (int i = 0; i < 8; ++i) {
        const int p = m0 + ty * 8 + i;
        if (p >= ce) continue;
        const int   n = list[e * NTOK + p];
        const float w = wgt[e * NTOK + p];
        float* op = out + (size_t)n * D_ + n0 + tx * 8;
#pragma unroll
        for (int j = 0; j < 8; ++j)
            atomicAdd(&op[j], w * (acc[i][j] + bb[j]));
    }
}

__global__ __launch_bounds__(256) void fallback_expert_kernel(
    const float* __restrict__ x,
    const float* __restrict__ W1, const float* __restrict__ b1,
    const float* __restrict__ W2, const float* __restrict__ b2,
    const int* __restrict__ top_idx, const float* __restrict__ top_w,
    float* __restrict__ out)
{
    __shared__ float x_lds[D_];
    __shared__ float h_lds[F_];

    const int n = blockIdx.x;
    const int t = threadIdx.x;

    ((float4*)x_lds)[t] = ((const float4*)(x + (size_t)n * D_))[t];
    __syncthreads();

    const int d0 = t * 4;
    float acc_out[4] = {0.f, 0.f, 0.f, 0.f};

    for (int k = 0; k < TOPK; ++k) {
        const int   e = top_idx[n * TOPK + k];
        const float w = top_w[n * TOPK + k];
        const float* W1e = W1 + (size_t)e * D_ * F_;
        const float* b1e = b1 + (size_t)e * F_;
#pragma unroll
        for (int tile = 0; tile < 2; ++tile) {
            const int base_f = tile * 2048 + t * 8;
            float a[8];
#pragma unroll
            for (int j = 0; j < 8; ++j) a[j] = b1e[base_f + j];
            const float4* wp = (const float4*)(W1e + base_f);
            for (int d = 0; d < D_; ++d) {
                const float4 w0 = wp[(size_t)d * (F_ / 4)];
                const float4 w1 = wp[(size_t)d * (F_ / 4) + 1];
                const float xv = x_lds[d];
                a[0] += xv * w0.x; a[1] += xv * w0.y;
                a[2] += xv * w0.z; a[3] += xv * w0.w;
                a[4] += xv * w1.x; a[5] += xv * w1.y;
                a[6] += xv * w1.z; a[7] += xv * w1.w;
            }
#pragma unroll
            for (int j = 0; j < 8; ++j)
                h_lds[base_f + j] = gelu_exact(a[j]);
        }
        __syncthreads();

        const float* W2e = W2 + (size_t)e * F_ * D_;
        const float* b2e = b2 + (size_t)e * D_;
        float y[4];
#pragma unroll
        for (int j = 0; j < 4; ++j) y[j] = b2e[d0 + j];
        const float4* wp2 = (const float4*)(W2e + d0);
        for (int f = 0; f < F_; ++f) {
            const float4 wv = wp2[(size_t)f * (D_ / 4)];
            const float hv = h_lds[f];
            y[0] += hv * wv.x; y[1] += hv * wv.y;
            y[2] += hv * wv.z; y[3] += hv * wv.w;
        }
#pragma unroll
        for (int j = 0; j < 4; ++j) acc_out[j] += w * y[j];
        __syncthreads();
    }

    float4 o; o.x = acc_out[0]; o.y = acc_out[1]; o.z = acc_out[2]; o.w = acc_out[3];
    *(float4*)(out + (size_t)n * D_ + d0) = o;
}

extern "C" void kernel_launch(void* const* d_in, const int* in_sizes, int n_in,
                              void* d_out, int out_size, void* d_ws, size_t ws_size,
                              hipStream_t stream) {
    const float* x  = (const float*)d_in[0];
    const float* Wr = (const float*)d_in[1];
    const float* W1 = (const float*)d_in[2];
    const float* b1 = (const float*)d_in[3];
    const float* W2 = (const float*)d_in[4];
    const float* b2 = (const float*)d_in[5];
    float* out = (float*)d_out;

    char* ws = (char*)d_ws;
    int*    cnt   = (int*)(ws + OFF_CNT);
    int*    basep = (int*)(ws + OFF_BASE);
    int*    tidx  = (int*)(ws + OFF_TIDX);
    float*  tw    = (float*)(ws + OFF_TW);
    int*    list  = (int*)(ws + OFF_LIST);
    float*  wgt   = (float*)(ws + OFF_WGT);

    if (ws_size >= WS_MFMA) {
        const int kslabs = (ws_size >= WS_MFMA2) ? 2 : 1;
        int*    slot = (int*)(ws + OFF_SLOT);
        bf16_t* Xb   = (bf16_t*)(ws + OFF_XB);
        bf16_t* W1T  = (bf16_t*)(ws + OFF_W1T);
        bf16_t* W2T  = (bf16_t*)(ws + OFF_W2T);
        bf16_t* H    = (bf16_t*)(ws + OFF_HN);
        float*  Y    = (float*)(ws + OFF_Y);

        hipMemsetAsync(cnt, 0, E_ * sizeof(int), stream);
        router_kernel<<<NTOK, 64, 0, stream>>>(x, Wr, tidx, tw, cnt, list, wgt, slot, 3);
        prefix_kernel<<<1, 64, 0, stream>>>(cnt, basep);
        convert_x_kernel<<<NTOK * D_ / 4 / 256, 256, 0, stream>>>(x, Xb);
        transpose_kernel<<<dim3(F_ / 64, D_ / 64, E_), 256, 0, stream>>>(W1, W1T, D_, F_);
        transpose_kernel<<<dim3(D_ / 64, F_ / 64, E_), 256, 0, stream>>>(W2, W2T, F_, D_);
        // 1-D grids, contiguous-working-prefix decode inside the kernel
        mg8_kernel<1><<<(NTOK / 256) * E_ * (F_ / 256), 512, 0, stream>>>(
            Xb, W1T, b1, cnt, basep, list, H, nullptr);
        mg8_kernel<2><<<(NTOK / 256) * E_ * kslabs * (D_ / 256), 512, 0, stream>>>(
            H, W2T, b2, cnt, basep, nullptr, nullptr, Y);
        combine_kernel<<<NTOK, 256, 0, stream>>>(Y, slot, tw, basep, out, kslabs);
    } else if (ws_size >= WS_OLD) {
        bf16_t* H = (bf16_t*)(ws + OFF_H_OLD);
        hipMemsetAsync(cnt, 0, E_ * sizeof(int), stream);
        router_kernel<<<NTOK, 64, 0, stream>>>(x, Wr, tidx, tw, cnt, list, wgt, nullptr, 1);
        prefix_kernel<<<1, 64, 0, stream>>>(cnt, basep);
        hipMemsetAsync(out, 0, (size_t)NTOK * D_ * sizeof(float), stream);
        gemm1_kernel<<<dim3(F_ / BN, NTOK / BM, E_), 256, 0, stream>>>(
            x, W1, b1, cnt, basep, list, H);
        gemm2_kernel<<<dim3(D_ / BN, NTOK / BM, E_), 256, 0, stream>>>(
            H, W2, b2, cnt, basep, list, wgt, out);
    } else {
        router_kernel<<<NTOK, 64, 0, stream>>>(x, Wr, tidx, tw, cnt, list, wgt, nullptr, 0);
        fallback_expert_kernel<<<NTOK, 256, 0, stream>>>(
            x, W1, b1, W2, b2, tidx, tw, out);
    }
}